// Round 1
// baseline (1303.660 us; speedup 1.0000x reference)
//
#include <hip/hip_runtime.h>
#include <math.h>

#define B 2
#define C 192
#define IMH 256
#define IMW 256
#define HW 65536
#define NH 4

// ---- ws layout (float offsets) ----
// qk_dw : [B][384][HW]   q=ch0..191, k=ch192..383 (post depthwise conv)
// raw   : [B][192][HW]   time-shared: pre-conv GEMM out, later V*attn out
// attnp : [4 splitK][8 bh][256][256] partial q^T k
// attnf : [8 bh][256][256] softmaxed attention
// normp : [16][48][256]  per-(b,h,q/k,cc) partial sums of squares
// norms : [16][256]      1/max(||col||,eps)
static constexpr long QKDW_OFF  = 0;
static constexpr long RAW_OFF   = 50331648;   // 2*384*65536
static constexpr long ATTNP_OFF = 75497472;   // +2*192*65536
static constexpr long ATTNF_OFF = 77594624;   // +4*8*65536
static constexpr long NORMP_OFF = 78118912;   // +8*65536
static constexpr long NORMS_OFF = 78315520;   // +16*48*256
// total floats = 78319616  (~313.3 MB)

// ---------------- pointwise GEMM (1x1 conv): out[b][oc][p] = sum_c in[b][c][p]*wt[(row_off+oc)*192+c]
__global__ __launch_bounds__(256) void gemm_pw(
    const float* __restrict__ in, const float* __restrict__ wt,
    float* __restrict__ out, int w_row_off, long out_bstride, int out_choff)
{
    __shared__ float Xs[8][256];
    __shared__ float Ws[8][64];
    const int tid = threadIdx.x;
    const long p0 = (long)blockIdx.x * 256;
    const int ocb = blockIdx.y * 64;
    const int b   = blockIdx.z;
    const float* inb = in + (long)b * C * HW + p0;

    float acc[8][8];
#pragma unroll
    for (int o = 0; o < 8; ++o)
#pragma unroll
        for (int p = 0; p < 8; ++p) acc[o][p] = 0.f;

    const int lk  = tid >> 5;         // 0..7  (X-load row)
    const int lc  = (tid & 31) * 4;   // 0..124 (X-load col)
    const int px0 = (tid & 31) * 4;   // my pixels: px0..px0+3 and px0+128..+131
    const int oc0 = (tid >> 5) * 8;   // my 8 out-channels

    for (int c0 = 0; c0 < C; c0 += 8) {
        const float* src = inb + (long)(c0 + lk) * HW + lc;
        *(float4*)&Xs[lk][lc]       = *(const float4*)src;
        *(float4*)&Xs[lk][lc + 128] = *(const float4*)(src + 128);
        {
            int f = tid * 2;
            int o = f & 63, kk = f >> 6;
            Ws[kk][o] = wt[(long)(w_row_off + ocb + o) * C + c0 + kk];
            o = (f + 1) & 63; kk = (f + 1) >> 6;
            Ws[kk][o] = wt[(long)(w_row_off + ocb + o) * C + c0 + kk];
        }
        __syncthreads();
#pragma unroll
        for (int kk = 0; kk < 8; ++kk) {
            float4 xa = *(float4*)&Xs[kk][px0];
            float4 xb = *(float4*)&Xs[kk][px0 + 128];
            float4 wa = *(float4*)&Ws[kk][oc0];
            float4 wb = *(float4*)&Ws[kk][oc0 + 4];
            float xv[8] = {xa.x, xa.y, xa.z, xa.w, xb.x, xb.y, xb.z, xb.w};
            float wv[8] = {wa.x, wa.y, wa.z, wa.w, wb.x, wb.y, wb.z, wb.w};
#pragma unroll
            for (int o = 0; o < 8; ++o)
#pragma unroll
                for (int p = 0; p < 8; ++p)
                    acc[o][p] = fmaf(wv[o], xv[p], acc[o][p]);
        }
        __syncthreads();
    }

    float* ob = out + (long)b * out_bstride + (long)(out_choff + ocb + oc0) * HW + p0;
#pragma unroll
    for (int o = 0; o < 8; ++o) {
        *(float4*)(ob + (long)o * HW + px0)       = make_float4(acc[o][0], acc[o][1], acc[o][2], acc[o][3]);
        *(float4*)(ob + (long)o * HW + px0 + 128) = make_float4(acc[o][4], acc[o][5], acc[o][6], acc[o][7]);
    }
}

// ---------------- depthwise 3x3, SAME zero pad, per-channel filter
__global__ __launch_bounds__(256) void dwconv(
    const float* __restrict__ in, const float* __restrict__ wdw,
    float* __restrict__ out, int w_ch_off, long out_bstride, int out_choff)
{
    const int tid = threadIdx.x;
    const int x = blockIdx.x * 64 + (tid & 63);
    const int y = blockIdx.y * 4 + (tid >> 6);
    const int bc = blockIdx.z;                 // b*192 + ch
    const int b = bc / 192, ch = bc % 192;
    const float* ip = in + (long)bc * HW;
    const float* wp = wdw + (long)(w_ch_off + ch) * 9;
    float s = 0.f;
#pragma unroll
    for (int dy = 0; dy < 3; ++dy) {
        int yy = y + dy - 1;
        if (yy < 0 || yy >= IMH) continue;
#pragma unroll
        for (int dx = 0; dx < 3; ++dx) {
            int xx = x + dx - 1;
            if (xx < 0 || xx >= IMW) continue;
            s = fmaf(ip[yy * IMW + xx], wp[dy * 3 + dx], s);
        }
    }
    out[(long)b * out_bstride + (long)(out_choff + ch) * HW + y * IMW + x] = s;
}

// ---------------- column L2-norm partials: per (b,h,q/k,cc,x) sum over y of val^2
__global__ __launch_bounds__(256) void norm_part(
    const float* __restrict__ qk, float* __restrict__ part)
{
    const int x = threadIdx.x;
    const int cc = blockIdx.x;              // 0..47
    const int g = blockIdx.y;               // b*8 + h*2 + qk  (0..15)
    const int b = g >> 3, h = (g >> 1) & 3, isk = g & 1;
    const float* p = qk + (long)(b * 384 + isk * 192 + h * 48 + cc) * HW + x;
    float s = 0.f;
    for (int yy = 0; yy < 256; ++yy) {
        float v = p[yy * 256];
        s = fmaf(v, v, s);
    }
    part[((long)g * 48 + cc) * 256 + x] = s;
}

__global__ __launch_bounds__(256) void norm_fin(
    const float* __restrict__ part, float* __restrict__ norms)
{
    const int x = threadIdx.x;
    const int g = blockIdx.x;               // 0..15
    float s = 0.f;
    for (int cc = 0; cc < 48; ++cc) s += part[((long)g * 48 + cc) * 256 + x];
    norms[g * 256 + x] = 1.f / fmaxf(sqrtf(s), 1e-12f);
}

// ---------------- attn partial GEMM: part[z][i][j] += q[:,i].k[:,j] over K-split
__global__ __launch_bounds__(256) void attn_gemm(
    const float* __restrict__ qk, float* __restrict__ part)
{
    __shared__ float Qs[16][64];
    __shared__ float Ks[16][64];
    const int tid = threadIdx.x;
    const int it = blockIdx.x * 64;
    const int jt = blockIdx.y * 64;
    const int z = blockIdx.z;               // bh*4 + sk
    const int bh = z >> 2, sk = z & 3;
    const int b = bh >> 2, h = bh & 3;
    const int lr = tid >> 4;                // 0..15
    const int lc = (tid & 15) * 4;
    const int i0 = (tid & 15) * 4;
    const int j0 = (tid >> 4) * 4;
    float acc[4][4];
#pragma unroll
    for (int a = 0; a < 4; ++a)
#pragma unroll
        for (int c2 = 0; c2 < 4; ++c2) acc[a][c2] = 0.f;

    const long qbase = (long)(b * 384 + h * 48) * HW;
    const long kbase = (long)(b * 384 + 192 + h * 48) * HW;
    const int kend = sk * 3072 + 3072;
    for (int k0 = sk * 3072; k0 < kend; k0 += 16) {
        const int cc = k0 >> 8;
        const int y0 = k0 & 255;
        const float* qp = qk + qbase + ((long)cc * 256 + y0 + lr) * 256 + it + lc;
        const float* kp = qk + kbase + ((long)cc * 256 + y0 + lr) * 256 + jt + lc;
        *(float4*)&Qs[lr][lc] = *(const float4*)qp;
        *(float4*)&Ks[lr][lc] = *(const float4*)kp;
        __syncthreads();
#pragma unroll
        for (int r = 0; r < 16; ++r) {
            float4 q4 = *(float4*)&Qs[r][i0];
            float4 k4 = *(float4*)&Ks[r][j0];
            float qv[4] = {q4.x, q4.y, q4.z, q4.w};
            float kv[4] = {k4.x, k4.y, k4.z, k4.w};
#pragma unroll
            for (int a = 0; a < 4; ++a)
#pragma unroll
                for (int c2 = 0; c2 < 4; ++c2)
                    acc[a][c2] = fmaf(qv[a], kv[c2], acc[a][c2]);
        }
        __syncthreads();
    }
    float* op = part + (long)z * 65536 + (long)(it + i0) * 256 + jt + j0;
#pragma unroll
    for (int a = 0; a < 4; ++a)
        *(float4*)(op + (long)a * 256) = make_float4(acc[a][0], acc[a][1], acc[a][2], acc[a][3]);
}

// ---------------- softmax over i (dim=-2), with 1/(|q_i||k_j|) and temperature applied first
__global__ __launch_bounds__(256) void softmax_k(
    const float* __restrict__ part, const float* __restrict__ norms,
    const float* __restrict__ temp, float* __restrict__ attn)
{
    __shared__ float red[4][64];
    const int tid = threadIdx.x;
    const int g = blockIdx.x;               // bh*4 + jq  (0..31)
    const int bh = g >> 2, jq = g & 3;
    const int b = bh >> 2, h = bh & 3;
    const int jl = tid & 63;
    const int j = jq * 64 + jl;
    const int iq = tid >> 6;
    const float* p = part + (long)bh * 262144;
    const float* inq = norms + (b * 8 + h * 2) * 256;
    const float invkj = norms[(b * 8 + h * 2 + 1) * 256 + j] * temp[h];

    float m = -1e30f;
    for (int i = iq * 64; i < iq * 64 + 64; ++i) {
        float s = p[i * 256 + j] + p[65536 + i * 256 + j] +
                  p[131072 + i * 256 + j] + p[196608 + i * 256 + j];
        m = fmaxf(m, s * inq[i] * invkj);
    }
    red[iq][jl] = m;
    __syncthreads();
    m = fmaxf(fmaxf(red[0][jl], red[1][jl]), fmaxf(red[2][jl], red[3][jl]));
    __syncthreads();

    float sum = 0.f;
    for (int i = iq * 64; i < iq * 64 + 64; ++i) {
        float s = p[i * 256 + j] + p[65536 + i * 256 + j] +
                  p[131072 + i * 256 + j] + p[196608 + i * 256 + j];
        sum += __expf(s * inq[i] * invkj - m);
    }
    red[iq][jl] = sum;
    __syncthreads();
    sum = red[0][jl] + red[1][jl] + red[2][jl] + red[3][jl];
    const float rs = 1.f / sum;

    for (int i = iq * 64; i < iq * 64 + 64; ++i) {
        float s = p[i * 256 + j] + p[65536 + i * 256 + j] +
                  p[131072 + i * 256 + j] + p[196608 + i * 256 + j];
        attn[(long)bh * 65536 + (long)i * 256 + j] = __expf(s * inq[i] * invkj - m) * rs;
    }
}

// ---------------- out[(cc,y), j] = sum_w v[(cc,y), w] * attn[w, j]
__global__ __launch_bounds__(256) void vattn_gemm(
    const float* __restrict__ v, const float* __restrict__ attn,
    float* __restrict__ outv)
{
    __shared__ float As[32][256];
    __shared__ float Vt[32][36];
    const int tid = threadIdx.x;
    const int mt = blockIdx.x;              // 0..383 (32-row tile of 12288)
    const int bh = blockIdx.y;
    const int b = bh >> 2, h = bh & 3;
    const int m0 = mt * 32;
    const int cc = m0 >> 8;
    const int y0 = m0 & 255;
    const long vbase = ((long)(b * 192 + h * 48 + cc) * 256 + y0) * 256;
    const int j0 = (tid & 63) * 4;
    const int r0 = (tid >> 6) * 8;
    const float* ap = attn + (long)bh * 65536;

    float acc[8][4];
#pragma unroll
    for (int r = 0; r < 8; ++r)
#pragma unroll
        for (int c2 = 0; c2 < 4; ++c2) acc[r][c2] = 0.f;

    for (int w0 = 0; w0 < 256; w0 += 32) {
#pragma unroll
        for (int t = 0; t < 8; ++t) {
            int f = tid + t * 256;
            int row = f >> 6, col = (f & 63) * 4;
            *(float4*)&As[row][col] = *(const float4*)(ap + (long)(w0 + row) * 256 + col);
        }
        {
            int r = tid >> 3, c4 = (tid & 7) * 4;
            float4 v4 = *(const float4*)(v + vbase + (long)r * 256 + w0 + c4);
            Vt[c4][r] = v4.x; Vt[c4 + 1][r] = v4.y; Vt[c4 + 2][r] = v4.z; Vt[c4 + 3][r] = v4.w;
        }
        __syncthreads();
#pragma unroll
        for (int w = 0; w < 32; ++w) {
            float4 a4 = *(float4*)&As[w][j0];
            float av[4] = {a4.x, a4.y, a4.z, a4.w};
            float4 va = *(float4*)&Vt[w][r0];
            float4 vb = *(float4*)&Vt[w][r0 + 4];
            float vv[8] = {va.x, va.y, va.z, va.w, vb.x, vb.y, vb.z, vb.w};
#pragma unroll
            for (int r = 0; r < 8; ++r)
#pragma unroll
                for (int c2 = 0; c2 < 4; ++c2)
                    acc[r][c2] = fmaf(vv[r], av[c2], acc[r][c2]);
        }
        __syncthreads();
    }
    float* op = outv + vbase + (long)r0 * 256 + j0;
#pragma unroll
    for (int r = 0; r < 8; ++r)
        *(float4*)(op + (long)r * 256) = make_float4(acc[r][0], acc[r][1], acc[r][2], acc[r][3]);
}

extern "C" void kernel_launch(void* const* d_in, const int* in_sizes, int n_in,
                              void* d_out, int out_size, void* d_ws, size_t ws_size,
                              hipStream_t stream)
{
    (void)in_sizes; (void)n_in; (void)out_size; (void)ws_size;
    const float* x      = (const float*)d_in[0];
    const float* w_qkv  = (const float*)d_in[1];
    const float* w_dw   = (const float*)d_in[2];
    const float* w_proj = (const float*)d_in[3];
    const float* temp   = (const float*)d_in[4];
    float* out = (float*)d_out;
    float* ws  = (float*)d_ws;

    float* qk_dw = ws + QKDW_OFF;
    float* raw   = ws + RAW_OFF;
    float* attnp = ws + ATTNP_OFF;
    float* attnf = ws + ATTNF_OFF;
    float* normp = ws + NORMP_OFF;
    float* norms = ws + NORMS_OFF;

    dim3 blk(256);
    const long obs_qk = 384L * HW;   // qk_dw per-batch stride
    const long obs_c  = (long)C * HW;

    // stage 1+2, group q -> qk_dw[ch 0..191]
    gemm_pw<<<dim3(256, 3, 2), blk, 0, stream>>>(x, w_qkv, raw, 0, obs_c, 0);
    dwconv <<<dim3(4, 64, 384), blk, 0, stream>>>(raw, w_dw, qk_dw, 0, obs_qk, 0);
    // group k -> qk_dw[ch 192..383]
    gemm_pw<<<dim3(256, 3, 2), blk, 0, stream>>>(x, w_qkv, raw, 192, obs_c, 0);
    dwconv <<<dim3(4, 64, 384), blk, 0, stream>>>(raw, w_dw, qk_dw, 192, obs_qk, 192);
    // group v -> d_out (time-shared; dead before final proj overwrites it)
    gemm_pw<<<dim3(256, 3, 2), blk, 0, stream>>>(x, w_qkv, raw, 384, obs_c, 0);
    dwconv <<<dim3(4, 64, 384), blk, 0, stream>>>(raw, w_dw, out, 384, obs_c, 0);

    // column norms of q,k
    norm_part<<<dim3(48, 16), blk, 0, stream>>>(qk_dw, normp);
    norm_fin <<<dim3(16), blk, 0, stream>>>(normp, norms);

    // attn = q^T k (split-K x4 partials)
    attn_gemm<<<dim3(4, 4, 32), blk, 0, stream>>>(qk_dw, attnp);
    // scale by 1/(|q||k|) * temperature, softmax over dim=-2
    softmax_k<<<dim3(32), blk, 0, stream>>>(attnp, norms, temp, attnf);

    // out = V * attn   (V lives in d_out; result into raw)
    vattn_gemm<<<dim3(384, 8), blk, 0, stream>>>(out, attnf, raw);

    // final 1x1 proj -> d_out
    gemm_pw<<<dim3(256, 3, 2), blk, 0, stream>>>(raw, w_proj, out, 0, obs_c, 0);
}

// Round 2
// 545.403 us; speedup vs baseline: 2.3903x; 2.3903x over previous
//
#include <hip/hip_runtime.h>
#include <math.h>

#define HW 65536

typedef float f32x4 __attribute__((ext_vector_type(4)));
typedef short bf16x8 __attribute__((ext_vector_type(8)));

// ---- ws layout (byte offsets) ----
// A0 region [0 .. 150,994,944): qkv_pre bf16 | { qkT bf16 (100,663,296) + Sp f32 @+100,663,296 (33,554,432) } | vout bf16 (50,331,648)
// A1 region [150,994,944 .. 301,989,888): xb bf16 | qkvp bf16 | voutT bf16
static constexpr size_t OFF_A0    = 0;
static constexpr size_t OFF_SP    = 100663296;
static constexpr size_t OFF_A1    = 150994944;
static constexpr size_t OFF_PT    = 301989888;  // 1,048,576 B
static constexpr size_t OFF_NORMS = 303038464;  // 16,384 B
static constexpr size_t OFF_WQ    = 303054848;  // 221,184 B
static constexpr size_t OFF_WP    = 303276032;  // 73,728 B   (end 303,349,760)

__device__ inline float b2f(unsigned short u) { union { unsigned u; float f; } v; v.u = ((unsigned)u) << 16; return v.f; }
__device__ inline unsigned short f2b(float f) {
    union { float f; unsigned u; } v; v.f = f;
    return (unsigned short)((v.u + 0x7fffu + ((v.u >> 16) & 1u)) >> 16);
}

// ---------------- convert weights to bf16
__global__ __launch_bounds__(256) void conv_w(const float* __restrict__ wq, const float* __restrict__ wp,
                                              unsigned short* __restrict__ wqb, unsigned short* __restrict__ wpb)
{
    int t = blockIdx.x * 256 + threadIdx.x;
    int stride = gridDim.x * 256;
    for (int i = t; i < 576 * 192; i += stride) wqb[i] = f2b(wq[i]);
    for (int i = t; i < 192 * 192; i += stride) wpb[i] = f2b(wp[i]);
}

// ---------------- x fp32 planar [b][192][HW] -> xb bf16 pixel-major [b*HW][192]
__global__ __launch_bounds__(256) void conv_x(const float* __restrict__ x, unsigned short* __restrict__ xb)
{
    __shared__ unsigned short T[64 * 200];   // [px 64][c 192 pad 200]
    int tid = threadIdx.x;
    int b = blockIdx.y;
    long p0 = (long)blockIdx.x * 64;
#pragma unroll
    for (int it = 0; it < 12; ++it) {
        int c = it * 16 + (tid >> 4);
        int px = (tid & 15) * 4;
        float4 v = *(const float4*)(x + ((long)b * 192 + c) * HW + p0 + px);
        T[(px + 0) * 200 + c] = f2b(v.x);
        T[(px + 1) * 200 + c] = f2b(v.y);
        T[(px + 2) * 200 + c] = f2b(v.z);
        T[(px + 3) * 200 + c] = f2b(v.w);
    }
    __syncthreads();
    int px = tid >> 2, q = tid & 3;
    unsigned short* ob = xb + ((long)b * HW + p0 + px) * 192 + q * 48;
#pragma unroll
    for (int e = 0; e < 6; ++e)
        *(bf16x8*)(ob + e * 8) = *(const bf16x8*)&T[px * 200 + q * 48 + e * 8];
}

// ---------------- MFMA GEMM: out[b][m][px] = sum_c A[m][c] * Bpix[b*HW+px][c], K=192
// out planar bf16 (outb) or fp32 (outf). block: M=64, N=256, 4 waves (2x2).
__global__ __launch_bounds__(256) void gemm_pm(const unsigned short* __restrict__ Aw,
                                               const unsigned short* __restrict__ Bp,
                                               unsigned short* __restrict__ outb,
                                               float* __restrict__ outf, int Mtot)
{
    int tid = threadIdx.x;
    int w = tid >> 6, lane = tid & 63, lg = lane >> 4, li = lane & 15;
    int wm = w >> 1, wn = w & 1;
    int oc0 = blockIdx.x * 64;
    long pflat = (long)blockIdx.y * 256;
    const unsigned short* ab = Aw + (long)(oc0 + wm * 32 + li) * 192 + lg * 8;
    const unsigned short* bb = Bp + (pflat + wn * 128 + li) * 192 + lg * 8;

    f32x4 acc[2][8];
#pragma unroll
    for (int i = 0; i < 2; ++i)
#pragma unroll
        for (int j = 0; j < 8; ++j) acc[i][j] = (f32x4){0.f, 0.f, 0.f, 0.f};

#pragma unroll 2
    for (int k0 = 0; k0 < 192; k0 += 32) {
        bf16x8 a0 = *(const bf16x8*)(ab + k0);
        bf16x8 a1 = *(const bf16x8*)(ab + 16 * 192 + k0);
#pragma unroll
        for (int fb = 0; fb < 8; ++fb) {
            bf16x8 bv = *(const bf16x8*)(bb + (long)fb * 16 * 192 + k0);
            acc[0][fb] = __builtin_amdgcn_mfma_f32_16x16x32_bf16(a0, bv, acc[0][fb], 0, 0, 0);
            acc[1][fb] = __builtin_amdgcn_mfma_f32_16x16x32_bf16(a1, bv, acc[1][fb], 0, 0, 0);
        }
    }

    int bb2 = (int)(blockIdx.y >> 8);            // batch
    int pxl = ((int)blockIdx.y & 255) * 256 + wn * 128;
#pragma unroll
    for (int fa = 0; fa < 2; ++fa) {
        int m = oc0 + wm * 32 + fa * 16 + lg * 4;
#pragma unroll
        for (int fb = 0; fb < 8; ++fb) {
            int px = pxl + fb * 16 + li;
            long base = ((long)bb2 * Mtot + m) * HW + px;
#pragma unroll
            for (int ii = 0; ii < 4; ++ii) {
                if (outf) outf[base + (long)ii * HW] = acc[fa][fb][ii];
                else      outb[base + (long)ii * HW] = f2b(acc[fa][fb][ii]);
            }
        }
    }
}

// ---------------- depthwise 3x3 SAME, bf16 in/out, LDS row staging. grid (32 ytiles, 1152 planes)
__global__ __launch_bounds__(256) void dwconv(const unsigned short* __restrict__ in,
                                              const float* __restrict__ wdw,
                                              unsigned short* __restrict__ out)
{
    __shared__ unsigned short Ls[10 * 256];
    int tid = threadIdx.x;
    int bc = blockIdx.y;
    int y0 = blockIdx.x * 8;
    const unsigned short* ip = in + (long)bc * HW;
    int ch = bc % 576;
    float w9[9];
#pragma unroll
    for (int t = 0; t < 9; ++t) w9[t] = wdw[ch * 9 + t];
#pragma unroll
    for (int it = 0; it < 2; ++it) {
        int idx = it * 256 + tid;
        if (idx < 320) {
            int r = idx >> 5, seg = (idx & 31) * 8;
            int gy = y0 - 1 + r;
            bf16x8 v = (bf16x8){0, 0, 0, 0, 0, 0, 0, 0};
            if (gy >= 0 && gy < 256) v = *(const bf16x8*)(ip + gy * 256 + seg);
            *(bf16x8*)&Ls[r * 256 + seg] = v;
        }
    }
    __syncthreads();
    int x = tid;
    unsigned short* ob = out + (long)bc * HW + (long)y0 * 256 + x;
#pragma unroll
    for (int yy = 0; yy < 8; ++yy) {
        float s = 0.f;
#pragma unroll
        for (int dy = 0; dy < 3; ++dy)
#pragma unroll
            for (int dx = 0; dx < 3; ++dx) {
                int xx = x + dx - 1;
                if (xx >= 0 && xx < 256)
                    s = fmaf(b2f(Ls[(yy + dy) * 256 + xx]), w9[dy * 3 + dx], s);
            }
        ob[yy * 256] = f2b(s);
    }
}

// ---------------- generic bf16 transpose (64x64 tiles).
// mode 0: q/k planar -> qkT[z][256][12288], z = b*8 + isk*4 + h
// mode 1: vout planar [b][192][HW] -> voutT [b*HW][192]
__global__ __launch_bounds__(256) void transpose_bf16(const unsigned short* __restrict__ src,
                                                      unsigned short* __restrict__ dst, int mode)
{
    __shared__ unsigned short T[64][72];
    int tid = threadIdx.x;
    int z = blockIdx.z;
    long so, dofs; int R, C;
    if (mode == 0) {
        int b = z >> 3, isk = (z >> 2) & 1, h = z & 3;
        so = ((long)(b * 576 + isk * 192 + h * 48)) * HW;
        dofs = (long)z * 12288 * 256;
        R = 12288; C = 256;
    } else {
        so = (long)z * 192 * HW;
        dofs = (long)z * HW * 192;
        R = 192; C = HW;
    }
    int r0 = blockIdx.y * 64, c0 = blockIdx.x * 64;
#pragma unroll
    for (int rr = 0; rr < 2; ++rr) {
        int r = rr * 32 + (tid >> 3);
        int cs = (tid & 7) * 8;
        *(bf16x8*)&T[r][cs] = *(const bf16x8*)(src + so + (long)(r0 + r) * C + c0 + cs);
    }
    __syncthreads();
#pragma unroll
    for (int cc = 0; cc < 2; ++cc) {
        int c = cc * 32 + (tid >> 3);
        int rs = (tid & 7) * 8;
        bf16x8 v;
#pragma unroll
        for (int e = 0; e < 8; ++e) v[e] = (short)T[rs + e][c];
        *(bf16x8*)(dst + dofs + (long)(c0 + c) * R + r0 + rs) = v;
    }
}

// ---------------- column norms: 1/max(||row of qkT||,eps). grid (256, 16)
__global__ __launch_bounds__(256) void norms_k(const unsigned short* __restrict__ qkT, float* __restrict__ norms)
{
    int i = blockIdx.x, z = blockIdx.y;
    const unsigned short* p = qkT + ((long)z * 256 + i) * 12288 + threadIdx.x * 8;
    float s = 0.f;
#pragma unroll
    for (int it = 0; it < 6; ++it) {
        bf16x8 v = *(const bf16x8*)(p + it * 2048);
#pragma unroll
        for (int e = 0; e < 8; ++e) { float f = b2f((unsigned short)v[e]); s = fmaf(f, f, s); }
    }
    for (int off = 32; off > 0; off >>= 1) s += __shfl_down(s, off, 64);
    __shared__ float r4[4];
    if ((threadIdx.x & 63) == 0) r4[threadIdx.x >> 6] = s;
    __syncthreads();
    if (threadIdx.x == 0) {
        float t = r4[0] + r4[1] + r4[2] + r4[3];
        norms[z * 256 + i] = 1.0f / fmaxf(sqrtf(t), 1e-12f);
    }
}

// ---------------- attn: Sp[sk][bh][i][j] partial of Q^T K. grid (2,2,128), K-chunk 768.
__global__ __launch_bounds__(256) void attn_qk(const unsigned short* __restrict__ qkT, float* __restrict__ Sp)
{
    __shared__ unsigned short Qs[128 * 40];
    __shared__ unsigned short Ks[128 * 40];
    int tid = threadIdx.x;
    int z = blockIdx.z; int bh = z >> 4, sk = z & 15; int b = bh >> 2, h = bh & 3;
    const unsigned short* qT = qkT + (long)(b * 8 + h) * 3145728;
    const unsigned short* kT = qkT + (long)(b * 8 + 4 + h) * 3145728;
    int i0 = blockIdx.x * 128, j0 = blockIdx.y * 128;
    int w = tid >> 6, lane = tid & 63, lg = lane >> 4, li = lane & 15;
    int wm = w >> 1, wn = w & 1;
    int srow = tid >> 2, sseg = (tid & 3) * 8;
    long qoff = (long)(i0 + srow) * 12288 + sk * 768 + sseg;
    long koff = (long)(j0 + srow) * 12288 + sk * 768 + sseg;

    f32x4 acc[4][4];
#pragma unroll
    for (int i = 0; i < 4; ++i)
#pragma unroll
        for (int j = 0; j < 4; ++j) acc[i][j] = (f32x4){0.f, 0.f, 0.f, 0.f};

    bf16x8 qr0 = *(const bf16x8*)(qT + qoff);
    bf16x8 qr1 = *(const bf16x8*)(qT + qoff + (long)64 * 12288);
    bf16x8 kr0 = *(const bf16x8*)(kT + koff);
    bf16x8 kr1 = *(const bf16x8*)(kT + koff + (long)64 * 12288);

#pragma unroll 1
    for (int ks = 0; ks < 24; ++ks) {
        *(bf16x8*)&Qs[srow * 40 + sseg] = qr0;
        *(bf16x8*)&Qs[(64 + srow) * 40 + sseg] = qr1;
        *(bf16x8*)&Ks[srow * 40 + sseg] = kr0;
        *(bf16x8*)&Ks[(64 + srow) * 40 + sseg] = kr1;
        if (ks < 23) {
            long o = (long)(ks + 1) * 32;
            qr0 = *(const bf16x8*)(qT + qoff + o);
            qr1 = *(const bf16x8*)(qT + qoff + (long)64 * 12288 + o);
            kr0 = *(const bf16x8*)(kT + koff + o);
            kr1 = *(const bf16x8*)(kT + koff + (long)64 * 12288 + o);
        }
        __syncthreads();
        bf16x8 af[4], bfr[4];
#pragma unroll
        for (int fa = 0; fa < 4; ++fa)
            af[fa] = *(const bf16x8*)&Qs[(wm * 64 + fa * 16 + li) * 40 + lg * 8];
#pragma unroll
        for (int fb = 0; fb < 4; ++fb)
            bfr[fb] = *(const bf16x8*)&Ks[(wn * 64 + fb * 16 + li) * 40 + lg * 8];
#pragma unroll
        for (int fa = 0; fa < 4; ++fa)
#pragma unroll
            for (int fb = 0; fb < 4; ++fb)
                acc[fa][fb] = __builtin_amdgcn_mfma_f32_16x16x32_bf16(af[fa], bfr[fb], acc[fa][fb], 0, 0, 0);
        __syncthreads();
    }

    float* op = Sp + ((long)(sk * 8 + bh) << 16);
#pragma unroll
    for (int fa = 0; fa < 4; ++fa) {
        int i = i0 + wm * 64 + fa * 16 + lg * 4;
#pragma unroll
        for (int fb = 0; fb < 4; ++fb) {
            int j = j0 + wn * 64 + fb * 16 + li;
#pragma unroll
            for (int ii = 0; ii < 4; ++ii)
                op[(long)(i + ii) * 256 + j] = acc[fa][fb][ii];
        }
    }
}

// ---------------- softmax over i with scaling; writes Pt[bh][j][i] bf16. grid (256): bh*32+jq
__global__ __launch_bounds__(256) void softmax_k(const float* __restrict__ Sp, const float* __restrict__ norms,
                                                 const float* __restrict__ temp, unsigned short* __restrict__ Pt)
{
    __shared__ float Sd[256 * 9];
    __shared__ float red[32 * 9];
    int tid = threadIdx.x;
    int g = blockIdx.x; int bh = g >> 5, jq = g & 31; int b = bh >> 2, h = bh & 3;
    int jl = tid & 7, iq = tid >> 3;
    int j = jq * 8 + jl;
    const float* nq = norms + (b * 8 + h) * 256;
    float invkj = norms[(b * 8 + 4 + h) * 256 + j] * temp[h];
    const float* sp = Sp + (long)bh * HW + j;

    float m = -1e30f;
#pragma unroll
    for (int ii = 0; ii < 8; ++ii) {
        int i = iq * 8 + ii;
        float s = 0.f;
#pragma unroll
        for (int sk = 0; sk < 16; ++sk) s += sp[((long)(sk * 8) << 16) + i * 256];
        float v = s * nq[i] * invkj;
        Sd[i * 9 + jl] = v;
        m = fmaxf(m, v);
    }
    red[iq * 9 + jl] = m;
    __syncthreads();
    m = -1e30f;
#pragma unroll
    for (int s2 = 0; s2 < 32; ++s2) m = fmaxf(m, red[s2 * 9 + jl]);
    __syncthreads();
    float sum = 0.f;
#pragma unroll
    for (int ii = 0; ii < 8; ++ii) sum += __expf(Sd[(iq * 8 + ii) * 9 + jl] - m);
    red[iq * 9 + jl] = sum;
    __syncthreads();
    sum = 0.f;
#pragma unroll
    for (int s2 = 0; s2 < 32; ++s2) sum += red[s2 * 9 + jl];
    float rs = 1.0f / sum;
    unsigned short* pt = Pt + (long)bh * HW + (long)j * 256;
#pragma unroll
    for (int ii = 0; ii < 8; ++ii) {
        int i = iq * 8 + ii;
        pt[i] = f2b(__expf(Sd[i * 9 + jl] - m) * rs);
    }
}

// ---------------- vattn: vout[b][ch][px] = sum_w V[m][w] * Pt[j][w]. grid (192, 8)
__global__ __launch_bounds__(256) void vattn(const unsigned short* __restrict__ qkvp,
                                             const unsigned short* __restrict__ Pt,
                                             unsigned short* __restrict__ vout)
{
    int tid = threadIdx.x;
    int w = tid >> 6, lane = tid & 63, lg = lane >> 4, li = lane & 15;
    int m0 = blockIdx.x * 64 + w * 16;
    int bh = blockIdx.y; int b = bh >> 2, h = bh & 3;
    const unsigned short* V = qkvp + ((long)(b * 576 + 384 + h * 48)) * HW;
    const unsigned short* P = Pt + (long)bh * HW;

    f32x4 acc[16];
#pragma unroll
    for (int i = 0; i < 16; ++i) acc[i] = (f32x4){0.f, 0.f, 0.f, 0.f};

#pragma unroll 1
    for (int ks = 0; ks < 8; ++ks) {
        bf16x8 a = *(const bf16x8*)(V + (long)(m0 + li) * 256 + ks * 32 + lg * 8);
#pragma unroll
        for (int fb = 0; fb < 16; ++fb) {
            bf16x8 bb = *(const bf16x8*)(P + (long)(fb * 16 + li) * 256 + ks * 32 + lg * 8);
            acc[fb] = __builtin_amdgcn_mfma_f32_16x16x32_bf16(a, bb, acc[fb], 0, 0, 0);
        }
    }
    unsigned short* ob = vout + (long)b * 192 * HW + (long)h * 48 * HW;
#pragma unroll
    for (int fb = 0; fb < 16; ++fb) {
#pragma unroll
        for (int ii = 0; ii < 4; ++ii) {
            int m = m0 + lg * 4 + ii;
            ob[((long)(m >> 8) << 16) + ((m & 255) << 8) + fb * 16 + li] = f2b(acc[fb][ii]);
        }
    }
}

extern "C" void kernel_launch(void* const* d_in, const int* in_sizes, int n_in,
                              void* d_out, int out_size, void* d_ws, size_t ws_size,
                              hipStream_t stream)
{
    (void)in_sizes; (void)n_in; (void)out_size; (void)ws_size;
    const float* x      = (const float*)d_in[0];
    const float* w_qkv  = (const float*)d_in[1];
    const float* w_dw   = (const float*)d_in[2];
    const float* w_proj = (const float*)d_in[3];
    const float* temp   = (const float*)d_in[4];
    float* out = (float*)d_out;
    char* ws = (char*)d_ws;

    unsigned short* qkv_pre = (unsigned short*)(ws + OFF_A0);
    unsigned short* qkT     = (unsigned short*)(ws + OFF_A0);
    float*          Sp      = (float*)(ws + OFF_SP);
    unsigned short* vout    = (unsigned short*)(ws + OFF_A0);
    unsigned short* xb      = (unsigned short*)(ws + OFF_A1);
    unsigned short* qkvp    = (unsigned short*)(ws + OFF_A1);
    unsigned short* voutT   = (unsigned short*)(ws + OFF_A1);
    unsigned short* Pt      = (unsigned short*)(ws + OFF_PT);
    float*          norms   = (float*)(ws + OFF_NORMS);
    unsigned short* wqb     = (unsigned short*)(ws + OFF_WQ);
    unsigned short* wpb     = (unsigned short*)(ws + OFF_WP);

    conv_w<<<64, 256, 0, stream>>>(w_qkv, w_proj, wqb, wpb);
    conv_x<<<dim3(1024, 2), 256, 0, stream>>>(x, xb);
    gemm_pm<<<dim3(9, 512), 256, 0, stream>>>(wqb, xb, qkv_pre, nullptr, 576);
    dwconv<<<dim3(32, 1152), 256, 0, stream>>>(qkv_pre, w_dw, qkvp);
    transpose_bf16<<<dim3(4, 192, 16), 256, 0, stream>>>(qkvp, qkT, 0);
    norms_k<<<dim3(256, 16), 256, 0, stream>>>(qkT, norms);
    attn_qk<<<dim3(2, 2, 128), 256, 0, stream>>>(qkT, Sp);
    softmax_k<<<256, 256, 0, stream>>>(Sp, norms, temp, Pt);
    vattn<<<dim3(192, 8), 256, 0, stream>>>(qkvp, Pt, vout);
    transpose_bf16<<<dim3(1024, 3, 2), 256, 0, stream>>>(vout, voutT, 1);
    gemm_pm<<<dim3(3, 512), 256, 0, stream>>>(wpb, voutT, nullptr, out, 192);
}

// Round 3
// 465.770 us; speedup vs baseline: 2.7989x; 1.1710x over previous
//
#include <hip/hip_runtime.h>
#include <math.h>

#define HW 65536

typedef float f32x4 __attribute__((ext_vector_type(4)));
typedef short bf16x8 __attribute__((ext_vector_type(8)));

// ---- ws layout (byte offsets) ----
static constexpr size_t OFF_A0    = 0;
static constexpr size_t OFF_SP    = 100663296;
static constexpr size_t OFF_A1    = 150994944;
static constexpr size_t OFF_PT    = 301989888;  // 1,048,576 B
static constexpr size_t OFF_NORMS = 303038464;  // 16,384 B
static constexpr size_t OFF_WQ    = 303054848;  // 221,184 B
static constexpr size_t OFF_WP    = 303276032;  // 73,728 B   (end 303,349,760)

__device__ inline float b2f(unsigned short u) { union { unsigned u; float f; } v; v.u = ((unsigned)u) << 16; return v.f; }
__device__ inline unsigned short f2b(float f) {
    union { float f; unsigned u; } v; v.f = f;
    return (unsigned short)((v.u + 0x7fffu + ((v.u >> 16) & 1u)) >> 16);
}

// ---------------- convert weights to bf16
__global__ __launch_bounds__(256) void conv_w(const float* __restrict__ wq, const float* __restrict__ wp,
                                              unsigned short* __restrict__ wqb, unsigned short* __restrict__ wpb)
{
    int t = blockIdx.x * 256 + threadIdx.x;
    int stride = gridDim.x * 256;
    for (int i = t; i < 576 * 192; i += stride) wqb[i] = f2b(wq[i]);
    for (int i = t; i < 192 * 192; i += stride) wpb[i] = f2b(wp[i]);
}

// ---------------- x fp32 planar [b][192][HW] -> xb bf16 pixel-major [b*HW][192]
__global__ __launch_bounds__(256) void conv_x(const float* __restrict__ x, unsigned short* __restrict__ xb)
{
    __shared__ unsigned short T[64 * 200];   // [px 64][c 192 pad 200]
    int tid = threadIdx.x;
    int b = blockIdx.y;
    long p0 = (long)blockIdx.x * 64;
#pragma unroll
    for (int it = 0; it < 12; ++it) {
        int c = it * 16 + (tid >> 4);
        int px = (tid & 15) * 4;
        float4 v = *(const float4*)(x + ((long)b * 192 + c) * HW + p0 + px);
        T[(px + 0) * 200 + c] = f2b(v.x);
        T[(px + 1) * 200 + c] = f2b(v.y);
        T[(px + 2) * 200 + c] = f2b(v.z);
        T[(px + 3) * 200 + c] = f2b(v.w);
    }
    __syncthreads();
    int px = tid >> 2, q = tid & 3;
    unsigned short* ob = xb + ((long)b * HW + p0 + px) * 192 + q * 48;
#pragma unroll
    for (int e = 0; e < 6; ++e)
        *(bf16x8*)(ob + e * 8) = *(const bf16x8*)&T[px * 200 + q * 48 + e * 8];
}

// ---------------- MFMA GEMM v2: one block owns a 128-pixel tile (LDS-staged once,
// fragments hoisted to registers), loops over all M-tiles of 64.
// out[b][m][px] = sum_c A[m][c] * Bpix[b*HW+px][c], K=192.
__global__ __launch_bounds__(256) void gemm_pm2(const unsigned short* __restrict__ Aw,
                                                const unsigned short* __restrict__ Bp,
                                                unsigned short* __restrict__ outb,
                                                float* __restrict__ outf, int Mtiles)
{
    __shared__ unsigned short Bs[128 * 200];
    int tid = threadIdx.x;
    int w = tid >> 6, lane = tid & 63, lg = lane >> 4, li = lane & 15;
    int wm = w >> 1, wn = w & 1;
    long pflat = (long)blockIdx.x * 128;

    // stage B tile [128 px][192 c] once
#pragma unroll
    for (int it = 0; it < 12; ++it) {
        int f = it * 256 + tid;
        int row = f / 24, cs = (f % 24) * 8;
        *(bf16x8*)&Bs[row * 200 + cs] = *(const bf16x8*)(Bp + (pflat + row) * 192 + cs);
    }
    __syncthreads();

    // hoist all B fragments for this wave's 64-px half into registers
    bf16x8 Bf[4][6];
#pragma unroll
    for (int fb = 0; fb < 4; ++fb)
#pragma unroll
        for (int ks = 0; ks < 6; ++ks)
            Bf[fb][ks] = *(const bf16x8*)&Bs[(wn * 64 + fb * 16 + li) * 200 + ks * 32 + lg * 8];

    const int b = (int)(blockIdx.x >> 9);
    const int pxl = ((int)blockIdx.x & 511) * 128 + wn * 64;
    const int Mtot = Mtiles * 64;

    for (int mt = 0; mt < Mtiles; ++mt) {
        int oc0 = mt * 64;
        const unsigned short* ab = Aw + (long)(oc0 + wm * 32 + li) * 192 + lg * 8;
        f32x4 acc[2][4];
#pragma unroll
        for (int i = 0; i < 2; ++i)
#pragma unroll
            for (int j = 0; j < 4; ++j) acc[i][j] = (f32x4){0.f, 0.f, 0.f, 0.f};
#pragma unroll
        for (int ks = 0; ks < 6; ++ks) {
            bf16x8 a0 = *(const bf16x8*)(ab + ks * 32);
            bf16x8 a1 = *(const bf16x8*)(ab + 16 * 192 + ks * 32);
#pragma unroll
            for (int fb = 0; fb < 4; ++fb) {
                acc[0][fb] = __builtin_amdgcn_mfma_f32_16x16x32_bf16(a0, Bf[fb][ks], acc[0][fb], 0, 0, 0);
                acc[1][fb] = __builtin_amdgcn_mfma_f32_16x16x32_bf16(a1, Bf[fb][ks], acc[1][fb], 0, 0, 0);
            }
        }
#pragma unroll
        for (int fa = 0; fa < 2; ++fa) {
            int m = oc0 + wm * 32 + fa * 16 + lg * 4;
#pragma unroll
            for (int fb = 0; fb < 4; ++fb) {
                int px = pxl + fb * 16 + li;
                long base = ((long)b * Mtot + m) * HW + px;
#pragma unroll
                for (int ii = 0; ii < 4; ++ii) {
                    if (outf) outf[base + (long)ii * HW] = acc[fa][fb][ii];
                    else      outb[base + (long)ii * HW] = f2b(acc[fa][fb][ii]);
                }
            }
        }
    }
}

// ---------------- depthwise 3x3 SAME, bf16 in/out, LDS row staging. grid (32 ytiles, 1152 planes)
__global__ __launch_bounds__(256) void dwconv(const unsigned short* __restrict__ in,
                                              const float* __restrict__ wdw,
                                              unsigned short* __restrict__ out)
{
    __shared__ unsigned short Ls[10 * 256];
    int tid = threadIdx.x;
    int bc = blockIdx.y;
    int y0 = blockIdx.x * 8;
    const unsigned short* ip = in + (long)bc * HW;
    int ch = bc % 576;
    float w9[9];
#pragma unroll
    for (int t = 0; t < 9; ++t) w9[t] = wdw[ch * 9 + t];
#pragma unroll
    for (int it = 0; it < 2; ++it) {
        int idx = it * 256 + tid;
        if (idx < 320) {
            int r = idx >> 5, seg = (idx & 31) * 8;
            int gy = y0 - 1 + r;
            bf16x8 v = (bf16x8){0, 0, 0, 0, 0, 0, 0, 0};
            if (gy >= 0 && gy < 256) v = *(const bf16x8*)(ip + gy * 256 + seg);
            *(bf16x8*)&Ls[r * 256 + seg] = v;
        }
    }
    __syncthreads();
    int x = tid;
    unsigned short* ob = out + (long)bc * HW + (long)y0 * 256 + x;
#pragma unroll
    for (int yy = 0; yy < 8; ++yy) {
        float s = 0.f;
#pragma unroll
        for (int dy = 0; dy < 3; ++dy)
#pragma unroll
            for (int dx = 0; dx < 3; ++dx) {
                int xx = x + dx - 1;
                if (xx >= 0 && xx < 256)
                    s = fmaf(b2f(Ls[(yy + dy) * 256 + xx]), w9[dy * 3 + dx], s);
            }
        ob[yy * 256] = f2b(s);
    }
}

// ---------------- generic bf16 transpose (64x64 tiles).
// mode 0: q/k planar -> qkT[z][256][12288], z = b*8 + isk*4 + h
// mode 1: vout planar [b][192][HW] -> voutT [b*HW][192]
__global__ __launch_bounds__(256) void transpose_bf16(const unsigned short* __restrict__ src,
                                                      unsigned short* __restrict__ dst, int mode)
{
    __shared__ unsigned short T[64][72];
    int tid = threadIdx.x;
    int z = blockIdx.z;
    long so, dofs; int R, C;
    if (mode == 0) {
        int b = z >> 3, isk = (z >> 2) & 1, h = z & 3;
        so = ((long)(b * 576 + isk * 192 + h * 48)) * HW;
        dofs = (long)z * 12288 * 256;
        R = 12288; C = 256;
    } else {
        so = (long)z * 192 * HW;
        dofs = (long)z * HW * 192;
        R = 192; C = HW;
    }
    int r0 = blockIdx.y * 64, c0 = blockIdx.x * 64;
#pragma unroll
    for (int rr = 0; rr < 2; ++rr) {
        int r = rr * 32 + (tid >> 3);
        int cs = (tid & 7) * 8;
        *(bf16x8*)&T[r][cs] = *(const bf16x8*)(src + so + (long)(r0 + r) * C + c0 + cs);
    }
    __syncthreads();
#pragma unroll
    for (int cc = 0; cc < 2; ++cc) {
        int c = cc * 32 + (tid >> 3);
        int rs = (tid & 7) * 8;
        bf16x8 v;
#pragma unroll
        for (int e = 0; e < 8; ++e) v[e] = (short)T[rs + e][c];
        *(bf16x8*)(dst + dofs + (long)(c0 + c) * R + r0 + rs) = v;
    }
}

// ---------------- column norms: 1/max(||row of qkT||,eps). grid (256, 16)
__global__ __launch_bounds__(256) void norms_k(const unsigned short* __restrict__ qkT, float* __restrict__ norms)
{
    int i = blockIdx.x, z = blockIdx.y;
    const unsigned short* p = qkT + ((long)z * 256 + i) * 12288 + threadIdx.x * 8;
    float s = 0.f;
#pragma unroll
    for (int it = 0; it < 6; ++it) {
        bf16x8 v = *(const bf16x8*)(p + it * 2048);
#pragma unroll
        for (int e = 0; e < 8; ++e) { float f = b2f((unsigned short)v[e]); s = fmaf(f, f, s); }
    }
    for (int off = 32; off > 0; off >>= 1) s += __shfl_down(s, off, 64);
    __shared__ float r4[4];
    if ((threadIdx.x & 63) == 0) r4[threadIdx.x >> 6] = s;
    __syncthreads();
    if (threadIdx.x == 0) {
        float t = r4[0] + r4[1] + r4[2] + r4[3];
        norms[z * 256 + i] = 1.0f / fmaxf(sqrtf(t), 1e-12f);
    }
}

// ---------------- attn: Sp[sk][bh][i][j] partial of Q^T K. grid (2,2,128), K-chunk 768.
__global__ __launch_bounds__(256) void attn_qk(const unsigned short* __restrict__ qkT, float* __restrict__ Sp)
{
    __shared__ unsigned short Qs[128 * 40];
    __shared__ unsigned short Ks[128 * 40];
    int tid = threadIdx.x;
    int z = blockIdx.z; int bh = z >> 4, sk = z & 15; int b = bh >> 2, h = bh & 3;
    const unsigned short* qT = qkT + (long)(b * 8 + h) * 3145728;
    const unsigned short* kT = qkT + (long)(b * 8 + 4 + h) * 3145728;
    int i0 = blockIdx.x * 128, j0 = blockIdx.y * 128;
    int w = tid >> 6, lane = tid & 63, lg = lane >> 4, li = lane & 15;
    int wm = w >> 1, wn = w & 1;
    int srow = tid >> 2, sseg = (tid & 3) * 8;
    long qoff = (long)(i0 + srow) * 12288 + sk * 768 + sseg;
    long koff = (long)(j0 + srow) * 12288 + sk * 768 + sseg;

    f32x4 acc[4][4];
#pragma unroll
    for (int i = 0; i < 4; ++i)
#pragma unroll
        for (int j = 0; j < 4; ++j) acc[i][j] = (f32x4){0.f, 0.f, 0.f, 0.f};

    bf16x8 qr0 = *(const bf16x8*)(qT + qoff);
    bf16x8 qr1 = *(const bf16x8*)(qT + qoff + (long)64 * 12288);
    bf16x8 kr0 = *(const bf16x8*)(kT + koff);
    bf16x8 kr1 = *(const bf16x8*)(kT + koff + (long)64 * 12288);

#pragma unroll 1
    for (int ks = 0; ks < 24; ++ks) {
        *(bf16x8*)&Qs[srow * 40 + sseg] = qr0;
        *(bf16x8*)&Qs[(64 + srow) * 40 + sseg] = qr1;
        *(bf16x8*)&Ks[srow * 40 + sseg] = kr0;
        *(bf16x8*)&Ks[(64 + srow) * 40 + sseg] = kr1;
        if (ks < 23) {
            long o = (long)(ks + 1) * 32;
            qr0 = *(const bf16x8*)(qT + qoff + o);
            qr1 = *(const bf16x8*)(qT + qoff + (long)64 * 12288 + o);
            kr0 = *(const bf16x8*)(kT + koff + o);
            kr1 = *(const bf16x8*)(kT + koff + (long)64 * 12288 + o);
        }
        __syncthreads();
        bf16x8 af[4], bfr[4];
#pragma unroll
        for (int fa = 0; fa < 4; ++fa)
            af[fa] = *(const bf16x8*)&Qs[(wm * 64 + fa * 16 + li) * 40 + lg * 8];
#pragma unroll
        for (int fb = 0; fb < 4; ++fb)
            bfr[fb] = *(const bf16x8*)&Ks[(wn * 64 + fb * 16 + li) * 40 + lg * 8];
#pragma unroll
        for (int fa = 0; fa < 4; ++fa)
#pragma unroll
            for (int fb = 0; fb < 4; ++fb)
                acc[fa][fb] = __builtin_amdgcn_mfma_f32_16x16x32_bf16(af[fa], bfr[fb], acc[fa][fb], 0, 0, 0);
        __syncthreads();
    }

    float* op = Sp + ((long)(sk * 8 + bh) << 16);
#pragma unroll
    for (int fa = 0; fa < 4; ++fa) {
        int i = i0 + wm * 64 + fa * 16 + lg * 4;
#pragma unroll
        for (int fb = 0; fb < 4; ++fb) {
            int j = j0 + wn * 64 + fb * 16 + li;
#pragma unroll
            for (int ii = 0; ii < 4; ++ii)
                op[(long)(i + ii) * 256 + j] = acc[fa][fb][ii];
        }
    }
}

// ---------------- softmax over i with scaling; writes Pt[bh][j][i] bf16. grid (256): bh*32+jq
__global__ __launch_bounds__(256) void softmax_k(const float* __restrict__ Sp, const float* __restrict__ norms,
                                                 const float* __restrict__ temp, unsigned short* __restrict__ Pt)
{
    __shared__ float Sd[256 * 9];
    __shared__ float red[32 * 9];
    int tid = threadIdx.x;
    int g = blockIdx.x; int bh = g >> 5, jq = g & 31; int b = bh >> 2, h = bh & 3;
    int jl = tid & 7, iq = tid >> 3;
    int j = jq * 8 + jl;
    const float* nq = norms + (b * 8 + h) * 256;
    float invkj = norms[(b * 8 + 4 + h) * 256 + j] * temp[h];
    const float* sp = Sp + (long)bh * HW + j;

    float m = -1e30f;
#pragma unroll
    for (int ii = 0; ii < 8; ++ii) {
        int i = iq * 8 + ii;
        float s = 0.f;
#pragma unroll
        for (int sk = 0; sk < 16; ++sk) s += sp[((long)(sk * 8) << 16) + i * 256];
        float v = s * nq[i] * invkj;
        Sd[i * 9 + jl] = v;
        m = fmaxf(m, v);
    }
    red[iq * 9 + jl] = m;
    __syncthreads();
    m = -1e30f;
#pragma unroll
    for (int s2 = 0; s2 < 32; ++s2) m = fmaxf(m, red[s2 * 9 + jl]);
    __syncthreads();
    float sum = 0.f;
#pragma unroll
    for (int ii = 0; ii < 8; ++ii) sum += __expf(Sd[(iq * 8 + ii) * 9 + jl] - m);
    red[iq * 9 + jl] = sum;
    __syncthreads();
    sum = 0.f;
#pragma unroll
    for (int s2 = 0; s2 < 32; ++s2) sum += red[s2 * 9 + jl];
    float rs = 1.0f / sum;
    unsigned short* pt = Pt + (long)bh * HW + (long)j * 256;
#pragma unroll
    for (int ii = 0; ii < 8; ++ii) {
        int i = iq * 8 + ii;
        pt[i] = f2b(__expf(Sd[i * 9 + jl] - m) * rs);
    }
}

// ---------------- vattn: vout[b][ch][px] = sum_w V[m][w] * Pt[j][w]. grid (192, 8)
__global__ __launch_bounds__(256) void vattn(const unsigned short* __restrict__ qkvp,
                                             const unsigned short* __restrict__ Pt,
                                             unsigned short* __restrict__ vout)
{
    int tid = threadIdx.x;
    int w = tid >> 6, lane = tid & 63, lg = lane >> 4, li = lane & 15;
    int m0 = blockIdx.x * 64 + w * 16;
    int bh = blockIdx.y; int b = bh >> 2, h = bh & 3;
    const unsigned short* V = qkvp + ((long)(b * 576 + 384 + h * 48)) * HW;
    const unsigned short* P = Pt + (long)bh * HW;

    f32x4 acc[16];
#pragma unroll
    for (int i = 0; i < 16; ++i) acc[i] = (f32x4){0.f, 0.f, 0.f, 0.f};

#pragma unroll 1
    for (int ks = 0; ks < 8; ++ks) {
        bf16x8 a = *(const bf16x8*)(V + (long)(m0 + li) * 256 + ks * 32 + lg * 8);
#pragma unroll
        for (int fb = 0; fb < 16; ++fb) {
            bf16x8 bb = *(const bf16x8*)(P + (long)(fb * 16 + li) * 256 + ks * 32 + lg * 8);
            acc[fb] = __builtin_amdgcn_mfma_f32_16x16x32_bf16(a, bb, acc[fb], 0, 0, 0);
        }
    }
    unsigned short* ob = vout + (long)b * 192 * HW + (long)h * 48 * HW;
#pragma unroll
    for (int fb = 0; fb < 16; ++fb) {
#pragma unroll
        for (int ii = 0; ii < 4; ++ii) {
            int m = m0 + lg * 4 + ii;
            ob[((long)(m >> 8) << 16) + ((m & 255) << 8) + fb * 16 + li] = f2b(acc[fb][ii]);
        }
    }
}

extern "C" void kernel_launch(void* const* d_in, const int* in_sizes, int n_in,
                              void* d_out, int out_size, void* d_ws, size_t ws_size,
                              hipStream_t stream)
{
    (void)in_sizes; (void)n_in; (void)out_size; (void)ws_size;
    const float* x      = (const float*)d_in[0];
    const float* w_qkv  = (const float*)d_in[1];
    const float* w_dw   = (const float*)d_in[2];
    const float* w_proj = (const float*)d_in[3];
    const float* temp   = (const float*)d_in[4];
    float* out = (float*)d_out;
    char* ws = (char*)d_ws;

    unsigned short* qkv_pre = (unsigned short*)(ws + OFF_A0);
    unsigned short* qkT     = (unsigned short*)(ws + OFF_A0);
    float*          Sp      = (float*)(ws + OFF_SP);
    unsigned short* vout    = (unsigned short*)(ws + OFF_A0);
    unsigned short* xb      = (unsigned short*)(ws + OFF_A1);
    unsigned short* qkvp    = (unsigned short*)(ws + OFF_A1);
    unsigned short* voutT   = (unsigned short*)(ws + OFF_A1);
    unsigned short* Pt      = (unsigned short*)(ws + OFF_PT);
    float*          norms   = (float*)(ws + OFF_NORMS);
    unsigned short* wqb     = (unsigned short*)(ws + OFF_WQ);
    unsigned short* wpb     = (unsigned short*)(ws + OFF_WP);

    conv_w<<<64, 256, 0, stream>>>(w_qkv, w_proj, wqb, wpb);
    conv_x<<<dim3(1024, 2), 256, 0, stream>>>(x, xb);
    gemm_pm2<<<1024, 256, 0, stream>>>(wqb, xb, qkv_pre, nullptr, 9);
    dwconv<<<dim3(32, 1152), 256, 0, stream>>>(qkv_pre, w_dw, qkvp);
    transpose_bf16<<<dim3(4, 192, 16), 256, 0, stream>>>(qkvp, qkT, 0);
    norms_k<<<dim3(256, 16), 256, 0, stream>>>(qkT, norms);
    attn_qk<<<dim3(2, 2, 128), 256, 0, stream>>>(qkT, Sp);
    softmax_k<<<256, 256, 0, stream>>>(Sp, norms, temp, Pt);
    vattn<<<dim3(192, 8), 256, 0, stream>>>(qkvp, Pt, vout);
    transpose_bf16<<<dim3(1024, 3, 2), 256, 0, stream>>>(vout, voutT, 1);
    gemm_pm2<<<1024, 256, 0, stream>>>(wpb, voutT, nullptr, out, 3);
}

// Round 4
// 402.017 us; speedup vs baseline: 3.2428x; 1.1586x over previous
//
#include <hip/hip_runtime.h>
#include <math.h>

#define HW 65536

typedef float f32x4 __attribute__((ext_vector_type(4)));
typedef short bf16x8 __attribute__((ext_vector_type(8)));

// ---- ws layout (byte offsets) ----
static constexpr size_t OFF_A0    = 0;
static constexpr size_t OFF_SP    = 100663296;
static constexpr size_t OFF_A1    = 150994944;
static constexpr size_t OFF_PT    = 301989888;  // 1,048,576 B
static constexpr size_t OFF_NORMS = 303038464;  // 16,384 B
static constexpr size_t OFF_WQ    = 303054848;  // 221,184 B
static constexpr size_t OFF_WP    = 303276032;  // 73,728 B   (end 303,349,760)

__device__ inline float b2f(unsigned short u) { union { unsigned u; float f; } v; v.u = ((unsigned)u) << 16; return v.f; }
__device__ inline unsigned short f2b(float f) {
    union { float f; unsigned u; } v; v.f = f;
    return (unsigned short)((v.u + 0x7fffu + ((v.u >> 16) & 1u)) >> 16);
}

// ---------------- convert weights to bf16
__global__ __launch_bounds__(256) void conv_w(const float* __restrict__ wq, const float* __restrict__ wp,
                                              unsigned short* __restrict__ wqb, unsigned short* __restrict__ wpb)
{
    int t = blockIdx.x * 256 + threadIdx.x;
    int stride = gridDim.x * 256;
    for (int i = t; i < 576 * 192; i += stride) wqb[i] = f2b(wq[i]);
    for (int i = t; i < 192 * 192; i += stride) wpb[i] = f2b(wp[i]);
}

// ---------------- x fp32 planar [b][192][HW] -> xb bf16 pixel-major [b*HW][192]
__global__ __launch_bounds__(256) void conv_x(const float* __restrict__ x, unsigned short* __restrict__ xb)
{
    __shared__ unsigned short T[64 * 200];   // [px 64][c 192 pad 200]
    int tid = threadIdx.x;
    int b = blockIdx.y;
    long p0 = (long)blockIdx.x * 64;
#pragma unroll
    for (int it = 0; it < 12; ++it) {
        int c = it * 16 + (tid >> 4);
        int px = (tid & 15) * 4;
        float4 v = *(const float4*)(x + ((long)b * 192 + c) * HW + p0 + px);
        T[(px + 0) * 200 + c] = f2b(v.x);
        T[(px + 1) * 200 + c] = f2b(v.y);
        T[(px + 2) * 200 + c] = f2b(v.z);
        T[(px + 3) * 200 + c] = f2b(v.w);
    }
    __syncthreads();
    int px = tid >> 2, q = tid & 3;
    unsigned short* ob = xb + ((long)b * HW + p0 + px) * 192 + q * 48;
#pragma unroll
    for (int e = 0; e < 6; ++e)
        *(bf16x8*)(ob + e * 8) = *(const bf16x8*)&T[px * 200 + q * 48 + e * 8];
}

// ---------------- MFMA GEMM v2: one block owns a 128-pixel tile (LDS-staged once,
// fragments hoisted to registers), loops over all M-tiles of 64.
__global__ __launch_bounds__(256) void gemm_pm2(const unsigned short* __restrict__ Aw,
                                                const unsigned short* __restrict__ Bp,
                                                unsigned short* __restrict__ outb,
                                                float* __restrict__ outf, int Mtiles)
{
    __shared__ unsigned short Bs[128 * 200];
    int tid = threadIdx.x;
    int w = tid >> 6, lane = tid & 63, lg = lane >> 4, li = lane & 15;
    int wm = w >> 1, wn = w & 1;
    long pflat = (long)blockIdx.x * 128;

#pragma unroll
    for (int it = 0; it < 12; ++it) {
        int f = it * 256 + tid;
        int row = f / 24, cs = (f % 24) * 8;
        *(bf16x8*)&Bs[row * 200 + cs] = *(const bf16x8*)(Bp + (pflat + row) * 192 + cs);
    }
    __syncthreads();

    bf16x8 Bf[4][6];
#pragma unroll
    for (int fb = 0; fb < 4; ++fb)
#pragma unroll
        for (int ks = 0; ks < 6; ++ks)
            Bf[fb][ks] = *(const bf16x8*)&Bs[(wn * 64 + fb * 16 + li) * 200 + ks * 32 + lg * 8];

    const int b = (int)(blockIdx.x >> 9);
    const int pxl = ((int)blockIdx.x & 511) * 128 + wn * 64;
    const int Mtot = Mtiles * 64;

    for (int mt = 0; mt < Mtiles; ++mt) {
        int oc0 = mt * 64;
        const unsigned short* ab = Aw + (long)(oc0 + wm * 32 + li) * 192 + lg * 8;
        f32x4 acc[2][4];
#pragma unroll
        for (int i = 0; i < 2; ++i)
#pragma unroll
            for (int j = 0; j < 4; ++j) acc[i][j] = (f32x4){0.f, 0.f, 0.f, 0.f};
#pragma unroll
        for (int ks = 0; ks < 6; ++ks) {
            bf16x8 a0 = *(const bf16x8*)(ab + ks * 32);
            bf16x8 a1 = *(const bf16x8*)(ab + 16 * 192 + ks * 32);
#pragma unroll
            for (int fb = 0; fb < 4; ++fb) {
                acc[0][fb] = __builtin_amdgcn_mfma_f32_16x16x32_bf16(a0, Bf[fb][ks], acc[0][fb], 0, 0, 0);
                acc[1][fb] = __builtin_amdgcn_mfma_f32_16x16x32_bf16(a1, Bf[fb][ks], acc[1][fb], 0, 0, 0);
            }
        }
#pragma unroll
        for (int fa = 0; fa < 2; ++fa) {
            int m = oc0 + wm * 32 + fa * 16 + lg * 4;
#pragma unroll
            for (int fb = 0; fb < 4; ++fb) {
                int px = pxl + fb * 16 + li;
                long base = ((long)b * Mtot + m) * HW + px;
#pragma unroll
                for (int ii = 0; ii < 4; ++ii) {
                    if (outf) outf[base + (long)ii * HW] = acc[fa][fb][ii];
                    else      outb[base + (long)ii * HW] = f2b(acc[fa][fb][ii]);
                }
            }
        }
    }
}

// ---------------- depthwise 3x3 SAME, bf16 in/out, LDS row staging. grid (32 ytiles, 1152 planes)
__global__ __launch_bounds__(256) void dwconv(const unsigned short* __restrict__ in,
                                              const float* __restrict__ wdw,
                                              unsigned short* __restrict__ out)
{
    __shared__ unsigned short Ls[10 * 256];
    int tid = threadIdx.x;
    int bc = blockIdx.y;
    int y0 = blockIdx.x * 8;
    const unsigned short* ip = in + (long)bc * HW;
    int ch = bc % 576;
    float w9[9];
#pragma unroll
    for (int t = 0; t < 9; ++t) w9[t] = wdw[ch * 9 + t];
#pragma unroll
    for (int it = 0; it < 2; ++it) {
        int idx = it * 256 + tid;
        if (idx < 320) {
            int r = idx >> 5, seg = (idx & 31) * 8;
            int gy = y0 - 1 + r;
            bf16x8 v = (bf16x8){0, 0, 0, 0, 0, 0, 0, 0};
            if (gy >= 0 && gy < 256) v = *(const bf16x8*)(ip + gy * 256 + seg);
            *(bf16x8*)&Ls[r * 256 + seg] = v;
        }
    }
    __syncthreads();
    int x = tid;
    unsigned short* ob = out + (long)bc * HW + (long)y0 * 256 + x;
#pragma unroll
    for (int yy = 0; yy < 8; ++yy) {
        float s = 0.f;
#pragma unroll
        for (int dy = 0; dy < 3; ++dy)
#pragma unroll
            for (int dx = 0; dx < 3; ++dx) {
                int xx = x + dx - 1;
                if (xx >= 0 && xx < 256)
                    s = fmaf(b2f(Ls[(yy + dy) * 256 + xx]), w9[dy * 3 + dx], s);
            }
        ob[yy * 256] = f2b(s);
    }
}

// ---------------- generic bf16 transpose (64x64 tiles).
__global__ __launch_bounds__(256) void transpose_bf16(const unsigned short* __restrict__ src,
                                                      unsigned short* __restrict__ dst, int mode)
{
    __shared__ unsigned short T[64][72];
    int tid = threadIdx.x;
    int z = blockIdx.z;
    long so, dofs; int R, C;
    if (mode == 0) {
        int b = z >> 3, isk = (z >> 2) & 1, h = z & 3;
        so = ((long)(b * 576 + isk * 192 + h * 48)) * HW;
        dofs = (long)z * 12288 * 256;
        R = 12288; C = 256;
    } else {
        so = (long)z * 192 * HW;
        dofs = (long)z * HW * 192;
        R = 192; C = HW;
    }
    int r0 = blockIdx.y * 64, c0 = blockIdx.x * 64;
#pragma unroll
    for (int rr = 0; rr < 2; ++rr) {
        int r = rr * 32 + (tid >> 3);
        int cs = (tid & 7) * 8;
        *(bf16x8*)&T[r][cs] = *(const bf16x8*)(src + so + (long)(r0 + r) * C + c0 + cs);
    }
    __syncthreads();
#pragma unroll
    for (int cc = 0; cc < 2; ++cc) {
        int c = cc * 32 + (tid >> 3);
        int rs = (tid & 7) * 8;
        bf16x8 v;
#pragma unroll
        for (int e = 0; e < 8; ++e) v[e] = (short)T[rs + e][c];
        *(bf16x8*)(dst + dofs + (long)(c0 + c) * R + r0 + rs) = v;
    }
}

// ---------------- column norms: 1/max(||row of qkT||,eps). grid (256, 16)
__global__ __launch_bounds__(256) void norms_k(const unsigned short* __restrict__ qkT, float* __restrict__ norms)
{
    int i = blockIdx.x, z = blockIdx.y;
    const unsigned short* p = qkT + ((long)z * 256 + i) * 12288 + threadIdx.x * 8;
    float s = 0.f;
#pragma unroll
    for (int it = 0; it < 6; ++it) {
        bf16x8 v = *(const bf16x8*)(p + it * 2048);
#pragma unroll
        for (int e = 0; e < 8; ++e) { float f = b2f((unsigned short)v[e]); s = fmaf(f, f, s); }
    }
    for (int off = 32; off > 0; off >>= 1) s += __shfl_down(s, off, 64);
    __shared__ float r4[4];
    if ((threadIdx.x & 63) == 0) r4[threadIdx.x >> 6] = s;
    __syncthreads();
    if (threadIdx.x == 0) {
        float t = r4[0] + r4[1] + r4[2] + r4[3];
        norms[z * 256 + i] = 1.0f / fmaxf(sqrtf(t), 1e-12f);
    }
}

// ---------------- attn: Sp[sk][bh][i][j] partial of Q^T K. grid (2,2,128), K-chunk 768.
__global__ __launch_bounds__(256) void attn_qk(const unsigned short* __restrict__ qkT, float* __restrict__ Sp)
{
    __shared__ unsigned short Qs[128 * 40];
    __shared__ unsigned short Ks[128 * 40];
    int tid = threadIdx.x;
    int z = blockIdx.z; int bh = z >> 4, sk = z & 15; int b = bh >> 2, h = bh & 3;
    const unsigned short* qT = qkT + (long)(b * 8 + h) * 3145728;
    const unsigned short* kT = qkT + (long)(b * 8 + 4 + h) * 3145728;
    int i0 = blockIdx.x * 128, j0 = blockIdx.y * 128;
    int w = tid >> 6, lane = tid & 63, lg = lane >> 4, li = lane & 15;
    int wm = w >> 1, wn = w & 1;
    int srow = tid >> 2, sseg = (tid & 3) * 8;
    long qoff = (long)(i0 + srow) * 12288 + sk * 768 + sseg;
    long koff = (long)(j0 + srow) * 12288 + sk * 768 + sseg;

    f32x4 acc[4][4];
#pragma unroll
    for (int i = 0; i < 4; ++i)
#pragma unroll
        for (int j = 0; j < 4; ++j) acc[i][j] = (f32x4){0.f, 0.f, 0.f, 0.f};

    bf16x8 qr0 = *(const bf16x8*)(qT + qoff);
    bf16x8 qr1 = *(const bf16x8*)(qT + qoff + (long)64 * 12288);
    bf16x8 kr0 = *(const bf16x8*)(kT + koff);
    bf16x8 kr1 = *(const bf16x8*)(kT + koff + (long)64 * 12288);

#pragma unroll 1
    for (int ks = 0; ks < 24; ++ks) {
        *(bf16x8*)&Qs[srow * 40 + sseg] = qr0;
        *(bf16x8*)&Qs[(64 + srow) * 40 + sseg] = qr1;
        *(bf16x8*)&Ks[srow * 40 + sseg] = kr0;
        *(bf16x8*)&Ks[(64 + srow) * 40 + sseg] = kr1;
        if (ks < 23) {
            long o = (long)(ks + 1) * 32;
            qr0 = *(const bf16x8*)(qT + qoff + o);
            qr1 = *(const bf16x8*)(qT + qoff + (long)64 * 12288 + o);
            kr0 = *(const bf16x8*)(kT + koff + o);
            kr1 = *(const bf16x8*)(kT + koff + (long)64 * 12288 + o);
        }
        __syncthreads();
        bf16x8 af[4], bfr[4];
#pragma unroll
        for (int fa = 0; fa < 4; ++fa)
            af[fa] = *(const bf16x8*)&Qs[(wm * 64 + fa * 16 + li) * 40 + lg * 8];
#pragma unroll
        for (int fb = 0; fb < 4; ++fb)
            bfr[fb] = *(const bf16x8*)&Ks[(wn * 64 + fb * 16 + li) * 40 + lg * 8];
#pragma unroll
        for (int fa = 0; fa < 4; ++fa)
#pragma unroll
            for (int fb = 0; fb < 4; ++fb)
                acc[fa][fb] = __builtin_amdgcn_mfma_f32_16x16x32_bf16(af[fa], bfr[fb], acc[fa][fb], 0, 0, 0);
        __syncthreads();
    }

    float* op = Sp + ((long)(sk * 8 + bh) << 16);
#pragma unroll
    for (int fa = 0; fa < 4; ++fa) {
        int i = i0 + wm * 64 + fa * 16 + lg * 4;
#pragma unroll
        for (int fb = 0; fb < 4; ++fb) {
            int j = j0 + wn * 64 + fb * 16 + li;
#pragma unroll
            for (int ii = 0; ii < 4; ++ii)
                op[(long)(i + ii) * 256 + j] = acc[fa][fb][ii];
        }
    }
}

// ---------------- softmax over i with scaling; writes Pt in vattn B-fragment layout.
// Pt elem (j,i) -> ((fb*8+ks)*64 + lg*16 + li)*8 + e, fb=j>>4, li=j&15, ks=i>>5, lg=(i>>3)&3, e=i&7
__global__ __launch_bounds__(256) void softmax_k(const float* __restrict__ Sp, const float* __restrict__ norms,
                                                 const float* __restrict__ temp, unsigned short* __restrict__ Pt)
{
    __shared__ float Sd[256 * 9];
    __shared__ float red[32 * 9];
    int tid = threadIdx.x;
    int g = blockIdx.x; int bh = g >> 5, jq = g & 31; int b = bh >> 2, h = bh & 3;
    int jl = tid & 7, iq = tid >> 3;
    int j = jq * 8 + jl;
    const float* nq = norms + (b * 8 + h) * 256;
    float invkj = norms[(b * 8 + 4 + h) * 256 + j] * temp[h];
    const float* sp = Sp + (long)bh * HW + j;

    float m = -1e30f;
#pragma unroll
    for (int ii = 0; ii < 8; ++ii) {
        int i = iq * 8 + ii;
        float s = 0.f;
#pragma unroll
        for (int sk = 0; sk < 16; ++sk) s += sp[((long)(sk * 8) << 16) + i * 256];
        float v = s * nq[i] * invkj;
        Sd[i * 9 + jl] = v;
        m = fmaxf(m, v);
    }
    red[iq * 9 + jl] = m;
    __syncthreads();
    m = -1e30f;
#pragma unroll
    for (int s2 = 0; s2 < 32; ++s2) m = fmaxf(m, red[s2 * 9 + jl]);
    __syncthreads();
    float sum = 0.f;
#pragma unroll
    for (int ii = 0; ii < 8; ++ii) sum += __expf(Sd[(iq * 8 + ii) * 9 + jl] - m);
    red[iq * 9 + jl] = sum;
    __syncthreads();
    sum = 0.f;
#pragma unroll
    for (int s2 = 0; s2 < 32; ++s2) sum += red[s2 * 9 + jl];
    float rs = 1.0f / sum;

    int fb = jq >> 1, li2 = (jq & 1) * 8 + jl;
    int ks = iq >> 2, lg = iq & 3;
    unsigned short* pt = Pt + (long)bh * HW + (long)((fb * 8 + ks) * 64 + lg * 16 + li2) * 8;
    bf16x8 pv;
#pragma unroll
    for (int ii = 0; ii < 8; ++ii)
        pv[ii] = (short)f2b(__expf(Sd[(iq * 8 + ii) * 9 + jl] - m) * rs);
    *(bf16x8*)pt = pv;
}

// ---------------- vattn v2: P in fragment layout (coalesced 1KB loads), no LDS.
// waves 2x2: wm over m (32 rows), wn over j (128 cols). grid (192, 8)
__global__ __launch_bounds__(256) void vattn(const unsigned short* __restrict__ qkvp,
                                             const unsigned short* __restrict__ Pt,
                                             unsigned short* __restrict__ vout)
{
    int tid = threadIdx.x;
    int w = tid >> 6, lane = tid & 63, lg = lane >> 4, li = lane & 15;
    int wm = w >> 1, wn = w & 1;
    int m0 = blockIdx.x * 64 + wm * 32;
    int bh = blockIdx.y; int b = bh >> 2, h = bh & 3;
    const unsigned short* V = qkvp + ((long)(b * 576 + 384 + h * 48)) * HW;
    const unsigned short* P = Pt + (long)bh * HW + wn * 32768 + lane * 8;

    f32x4 acc[2][8];
#pragma unroll
    for (int i = 0; i < 2; ++i)
#pragma unroll
        for (int j = 0; j < 8; ++j) acc[i][j] = (f32x4){0.f, 0.f, 0.f, 0.f};

#pragma unroll 2
    for (int ks = 0; ks < 8; ++ks) {
        bf16x8 a0 = *(const bf16x8*)(V + (long)(m0 + li) * 256 + ks * 32 + lg * 8);
        bf16x8 a1 = *(const bf16x8*)(V + (long)(m0 + 16 + li) * 256 + ks * 32 + lg * 8);
#pragma unroll
        for (int fb2 = 0; fb2 < 8; ++fb2) {
            bf16x8 bb = *(const bf16x8*)(P + (fb2 * 8 + ks) * 512);
            acc[0][fb2] = __builtin_amdgcn_mfma_f32_16x16x32_bf16(a0, bb, acc[0][fb2], 0, 0, 0);
            acc[1][fb2] = __builtin_amdgcn_mfma_f32_16x16x32_bf16(a1, bb, acc[1][fb2], 0, 0, 0);
        }
    }
    unsigned short* ob = vout + (long)(b * 192 + h * 48) * HW;
#pragma unroll
    for (int fa = 0; fa < 2; ++fa) {
#pragma unroll
        for (int fb2 = 0; fb2 < 8; ++fb2) {
            int j = (wn * 8 + fb2) * 16 + li;
#pragma unroll
            for (int ii = 0; ii < 4; ++ii) {
                int m = m0 + fa * 16 + lg * 4 + ii;
                ob[((long)(m >> 8) << 16) + ((m & 255) << 8) + j] = f2b(acc[fa][fb2][ii]);
            }
        }
    }
}

extern "C" void kernel_launch(void* const* d_in, const int* in_sizes, int n_in,
                              void* d_out, int out_size, void* d_ws, size_t ws_size,
                              hipStream_t stream)
{
    (void)in_sizes; (void)n_in; (void)out_size; (void)ws_size;
    const float* x      = (const float*)d_in[0];
    const float* w_qkv  = (const float*)d_in[1];
    const float* w_dw   = (const float*)d_in[2];
    const float* w_proj = (const float*)d_in[3];
    const float* temp   = (const float*)d_in[4];
    float* out = (float*)d_out;
    char* ws = (char*)d_ws;

    unsigned short* qkv_pre = (unsigned short*)(ws + OFF_A0);
    unsigned short* qkT     = (unsigned short*)(ws + OFF_A0);
    float*          Sp      = (float*)(ws + OFF_SP);
    unsigned short* vout    = (unsigned short*)(ws + OFF_A0);
    unsigned short* xb      = (unsigned short*)(ws + OFF_A1);
    unsigned short* qkvp    = (unsigned short*)(ws + OFF_A1);
    unsigned short* voutT   = (unsigned short*)(ws + OFF_A1);
    unsigned short* Pt      = (unsigned short*)(ws + OFF_PT);
    float*          norms   = (float*)(ws + OFF_NORMS);
    unsigned short* wqb     = (unsigned short*)(ws + OFF_WQ);
    unsigned short* wpb     = (unsigned short*)(ws + OFF_WP);

    conv_w<<<64, 256, 0, stream>>>(w_qkv, w_proj, wqb, wpb);
    conv_x<<<dim3(1024, 2), 256, 0, stream>>>(x, xb);
    gemm_pm2<<<1024, 256, 0, stream>>>(wqb, xb, qkv_pre, nullptr, 9);
    dwconv<<<dim3(32, 1152), 256, 0, stream>>>(qkv_pre, w_dw, qkvp);
    transpose_bf16<<<dim3(4, 192, 16), 256, 0, stream>>>(qkvp, qkT, 0);
    norms_k<<<dim3(256, 16), 256, 0, stream>>>(qkT, norms);
    attn_qk<<<dim3(2, 2, 128), 256, 0, stream>>>(qkT, Sp);
    softmax_k<<<256, 256, 0, stream>>>(Sp, norms, temp, Pt);
    vattn<<<dim3(192, 8), 256, 0, stream>>>(qkvp, Pt, vout);
    transpose_bf16<<<dim3(1024, 3, 2), 256, 0, stream>>>(vout, voutT, 1);
    gemm_pm2<<<1024, 256, 0, stream>>>(wpb, voutT, nullptr, out, 3);
}

// Round 5
// 317.331 us; speedup vs baseline: 4.1082x; 1.2669x over previous
//
#include <hip/hip_runtime.h>
#include <math.h>

#define HW 65536

typedef float f32x4 __attribute__((ext_vector_type(4)));
typedef short bf16x8 __attribute__((ext_vector_type(8)));
typedef short bf16x4 __attribute__((ext_vector_type(4)));

// ---- ws layout (byte offsets) ----
// A0 [0 .. 150,994,944): qkv_pre bf16 (151MB) ; later Sp f32 @+100,663,296 ; vout bf16 @0 (50.3MB)
// A1 [150,994,944 .. 301,989,888): qkT bf16 (100,663,296) + vpl bf16 (50,331,648)
static constexpr size_t OFF_A0    = 0;
static constexpr size_t OFF_SP    = 100663296;
static constexpr size_t OFF_QKT   = 150994944;
static constexpr size_t OFF_VPL   = 251658240;
static constexpr size_t OFF_PT    = 301989888;  // 1,048,576 B
static constexpr size_t OFF_NORMS = 303038464;  // 16,384 B
static constexpr size_t OFF_WQ    = 303054848;  // 221,184 B
static constexpr size_t OFF_WP    = 303276032;  // 73,728 B   (end 303,349,760)

__device__ inline float b2f(unsigned short u) { union { unsigned u; float f; } v; v.u = ((unsigned)u) << 16; return v.f; }
__device__ inline unsigned short f2b(float f) {
    union { float f; unsigned u; } v; v.f = f;
    return (unsigned short)((v.u + 0x7fffu + ((v.u >> 16) & 1u)) >> 16);
}

// ---------------- convert weights to bf16
__global__ __launch_bounds__(256) void conv_w(const float* __restrict__ wq, const float* __restrict__ wp,
                                              unsigned short* __restrict__ wqb, unsigned short* __restrict__ wpb)
{
    int t = blockIdx.x * 256 + threadIdx.x;
    int stride = gridDim.x * 256;
    for (int i = t; i < 576 * 192; i += stride) wqb[i] = f2b(wq[i]);
    for (int i = t; i < 192 * 192; i += stride) wpb[i] = f2b(wp[i]);
}

// ---------------- MFMA GEMM v3: B staged from PLANAR source into LDS [192 ch][130 px-pad],
// fragments gathered via scalar u16 reads (PAD=130 -> lg-groups 8 banks apart, conflict-free).
// MODE 0: qkv (src f32 planar x, out bf16 planar). MODE 1: proj (src bf16 planar, out f32).
template <int MODE>
__global__ __launch_bounds__(256) void gemm_pm3(const unsigned short* __restrict__ Aw,
                                                const void* __restrict__ Bsrc,
                                                unsigned short* __restrict__ outb,
                                                float* __restrict__ outf, int Mtiles)
{
    __shared__ unsigned short Bs[192 * 130];
    int tid = threadIdx.x;
    int w = tid >> 6, lane = tid & 63, lg = lane >> 4, li = lane & 15;
    int wm = w >> 1, wn = w & 1;
    const int b = (int)(blockIdx.x >> 9);
    const long px0 = (long)(blockIdx.x & 511) * 128;

    if (MODE == 0) {
        const float* X = (const float*)Bsrc;
#pragma unroll
        for (int it = 0; it < 24; ++it) {
            int task = it * 256 + tid;               // 6144 = 192ch * 32seg
            int ch = task >> 5, seg = task & 31;
            float4 v = *(const float4*)(X + ((long)(b * 192 + ch)) * HW + px0 + seg * 4);
            unsigned* d32 = (unsigned*)&Bs[ch * 130 + seg * 4];   // 4B aligned
            d32[0] = (unsigned)f2b(v.x) | ((unsigned)f2b(v.y) << 16);
            d32[1] = (unsigned)f2b(v.z) | ((unsigned)f2b(v.w) << 16);
        }
    } else {
        const unsigned short* X = (const unsigned short*)Bsrc;
#pragma unroll
        for (int it = 0; it < 12; ++it) {
            int task = it * 256 + tid;               // 3072 = 192ch * 16seg
            int ch = task >> 4, seg = task & 15;
            bf16x8 v = *(const bf16x8*)(X + ((long)(b * 192 + ch)) * HW + px0 + seg * 8);
            unsigned* d32 = (unsigned*)&Bs[ch * 130 + seg * 8];   // 4B aligned
            const unsigned* s32 = (const unsigned*)&v;
            d32[0] = s32[0]; d32[1] = s32[1]; d32[2] = s32[2]; d32[3] = s32[3];
        }
    }
    __syncthreads();

    // gather B fragments: Bf[fb][ks][e] = Bs[(ks*32+lg*8+e)][px]
    bf16x8 Bf[4][6];
#pragma unroll
    for (int fb = 0; fb < 4; ++fb) {
        int px = wn * 64 + fb * 16 + li;
#pragma unroll
        for (int ks = 0; ks < 6; ++ks) {
            bf16x8 v;
#pragma unroll
            for (int e = 0; e < 8; ++e)
                v[e] = (short)Bs[(ks * 32 + lg * 8 + e) * 130 + px];
            Bf[fb][ks] = v;
        }
    }

    const int pxl = (int)(px0) + wn * 64;
    const int Mtot = Mtiles * 64;

    for (int mt = 0; mt < Mtiles; ++mt) {
        int oc0 = mt * 64;
        const unsigned short* ab = Aw + (long)(oc0 + wm * 32 + li) * 192 + lg * 8;
        f32x4 acc[2][4];
#pragma unroll
        for (int i = 0; i < 2; ++i)
#pragma unroll
            for (int j = 0; j < 4; ++j) acc[i][j] = (f32x4){0.f, 0.f, 0.f, 0.f};
#pragma unroll
        for (int ks = 0; ks < 6; ++ks) {
            bf16x8 a0 = *(const bf16x8*)(ab + ks * 32);
            bf16x8 a1 = *(const bf16x8*)(ab + 16 * 192 + ks * 32);
#pragma unroll
            for (int fb = 0; fb < 4; ++fb) {
                acc[0][fb] = __builtin_amdgcn_mfma_f32_16x16x32_bf16(a0, Bf[fb][ks], acc[0][fb], 0, 0, 0);
                acc[1][fb] = __builtin_amdgcn_mfma_f32_16x16x32_bf16(a1, Bf[fb][ks], acc[1][fb], 0, 0, 0);
            }
        }
#pragma unroll
        for (int fa = 0; fa < 2; ++fa) {
            int m = oc0 + wm * 32 + fa * 16 + lg * 4;
#pragma unroll
            for (int fb = 0; fb < 4; ++fb) {
                int px = pxl + fb * 16 + li;
                long base = ((long)b * Mtot + m) * HW + px;
#pragma unroll
                for (int ii = 0; ii < 4; ++ii) {
                    if (MODE == 1) outf[base + (long)ii * HW] = acc[fa][fb][ii];
                    else           outb[base + (long)ii * HW] = f2b(acc[fa][fb][ii]);
                }
            }
        }
    }
}

// ---------------- depthwise 3x3 SAME v2: 32-row strips, aligned b64 LDS reads,
// 4x x 8y outputs/thread; q/k written directly in qkT layout, v planar.
// grid (8 ystrips, 1152 planes = b*576+ch3)
__global__ __launch_bounds__(256) void dwconv2(const unsigned short* __restrict__ in,
                                               const float* __restrict__ wdw,
                                               unsigned short* __restrict__ qkT,
                                               unsigned short* __restrict__ vpl)
{
    __shared__ unsigned short Ls[34 * 272];   // rows y0-1..y0+32, x at offset 8, zero pads 0..7 & 264..271
    int tid = threadIdx.x;
    int zp = blockIdx.y;
    int b = zp / 576, ch3 = zp % 576;
    int y0 = blockIdx.x * 32;
    const unsigned short* ip = in + (long)zp * HW;
    float w9[9];
#pragma unroll
    for (int t = 0; t < 9; ++t) w9[t] = wdw[ch3 * 9 + t];

    const bf16x8 z8 = (bf16x8){0, 0, 0, 0, 0, 0, 0, 0};
    if (tid < 34)               *(bf16x8*)&Ls[tid * 272] = z8;
    else if (tid < 68)          *(bf16x8*)&Ls[(tid - 34) * 272 + 264] = z8;
#pragma unroll
    for (int it = 0; it < 5; ++it) {
        int task = it * 256 + tid;
        if (task < 1088) {
            int r = task >> 5, seg = task & 31;
            int gy = y0 - 1 + r;
            bf16x8 v = z8;
            if (gy >= 0 && gy < 256) v = *(const bf16x8*)(ip + gy * 256 + seg * 8);
            *(bf16x8*)&Ls[r * 272 + 8 + seg * 8] = v;
        }
    }
    __syncthreads();

    int xg = tid & 63, yg = tid >> 6;
    int x0 = xg * 4;
    float acc[8][4];
#pragma unroll
    for (int yy = 0; yy < 8; ++yy)
#pragma unroll
        for (int xi = 0; xi < 4; ++xi) acc[yy][xi] = 0.f;

#pragma unroll
    for (int rr = 0; rr < 10; ++rr) {
        const unsigned short* lp = &Ls[(yg * 8 + rr) * 272 + 8 + x0];
        bf16x4 A  = *(const bf16x4*)(lp - 4);
        bf16x4 Bv = *(const bf16x4*)(lp);
        bf16x4 Cv = *(const bf16x4*)(lp + 4);
        float f[6] = { b2f((unsigned short)A[3]),  b2f((unsigned short)Bv[0]),
                       b2f((unsigned short)Bv[1]), b2f((unsigned short)Bv[2]),
                       b2f((unsigned short)Bv[3]), b2f((unsigned short)Cv[0]) };
#pragma unroll
        for (int dy = 0; dy < 3; ++dy) {
            int yy = rr - dy;
            if (yy >= 0 && yy < 8) {
#pragma unroll
                for (int dx = 0; dx < 3; ++dx)
#pragma unroll
                    for (int xi = 0; xi < 4; ++xi)
                        acc[yy][xi] = fmaf(w9[dy * 3 + dx], f[dx + xi], acc[yy][xi]);
            }
        }
    }

    if (ch3 < 384) {
        int isk = ch3 >= 192 ? 1 : 0;
        int chq = ch3 - isk * 192;
        int hh = chq / 48, cc = chq % 48;
        long zbase = (long)(b * 8 + isk * 4 + hh) * 3145728L + (long)cc * 256 + y0 + yg * 8;
#pragma unroll
        for (int xi = 0; xi < 4; ++xi) {
            bf16x8 pv;
#pragma unroll
            for (int yy = 0; yy < 8; ++yy) pv[yy] = (short)f2b(acc[yy][xi]);
            *(bf16x8*)(qkT + zbase + (long)(x0 + xi) * 12288) = pv;
        }
    } else {
        unsigned short* ob = vpl + (long)(b * 192 + ch3 - 384) * HW + (long)(y0 + yg * 8) * 256 + x0;
#pragma unroll
        for (int yy = 0; yy < 8; ++yy) {
            bf16x4 pv;
#pragma unroll
            for (int xi = 0; xi < 4; ++xi) pv[xi] = (short)f2b(acc[yy][xi]);
            *(bf16x4*)(ob + yy * 256) = pv;
        }
    }
}

// ---------------- column norms: 1/max(||row of qkT||,eps). grid (256, 16)
__global__ __launch_bounds__(256) void norms_k(const unsigned short* __restrict__ qkT, float* __restrict__ norms)
{
    int i = blockIdx.x, z = blockIdx.y;
    const unsigned short* p = qkT + ((long)z * 256 + i) * 12288 + threadIdx.x * 8;
    float s = 0.f;
#pragma unroll
    for (int it = 0; it < 6; ++it) {
        bf16x8 v = *(const bf16x8*)(p + it * 2048);
#pragma unroll
        for (int e = 0; e < 8; ++e) { float f = b2f((unsigned short)v[e]); s = fmaf(f, f, s); }
    }
    for (int off = 32; off > 0; off >>= 1) s += __shfl_down(s, off, 64);
    __shared__ float r4[4];
    if ((threadIdx.x & 63) == 0) r4[threadIdx.x >> 6] = s;
    __syncthreads();
    if (threadIdx.x == 0) {
        float t = r4[0] + r4[1] + r4[2] + r4[3];
        norms[z * 256 + i] = 1.0f / fmaxf(sqrtf(t), 1e-12f);
    }
}

// ---------------- attn: Sp[sk][bh][i][j] partial of Q^T K. grid (2,2,128), K-chunk 768.
__global__ __launch_bounds__(256) void attn_qk(const unsigned short* __restrict__ qkT, float* __restrict__ Sp)
{
    __shared__ unsigned short Qs[128 * 40];
    __shared__ unsigned short Ks[128 * 40];
    int tid = threadIdx.x;
    int z = blockIdx.z; int bh = z >> 4, sk = z & 15; int b = bh >> 2, h = bh & 3;
    const unsigned short* qT = qkT + (long)(b * 8 + h) * 3145728;
    const unsigned short* kT = qkT + (long)(b * 8 + 4 + h) * 3145728;
    int i0 = blockIdx.x * 128, j0 = blockIdx.y * 128;
    int w = tid >> 6, lane = tid & 63, lg = lane >> 4, li = lane & 15;
    int wm = w >> 1, wn = w & 1;
    int srow = tid >> 2, sseg = (tid & 3) * 8;
    long qoff = (long)(i0 + srow) * 12288 + sk * 768 + sseg;
    long koff = (long)(j0 + srow) * 12288 + sk * 768 + sseg;

    f32x4 acc[4][4];
#pragma unroll
    for (int i = 0; i < 4; ++i)
#pragma unroll
        for (int j = 0; j < 4; ++j) acc[i][j] = (f32x4){0.f, 0.f, 0.f, 0.f};

    bf16x8 qr0 = *(const bf16x8*)(qT + qoff);
    bf16x8 qr1 = *(const bf16x8*)(qT + qoff + (long)64 * 12288);
    bf16x8 kr0 = *(const bf16x8*)(kT + koff);
    bf16x8 kr1 = *(const bf16x8*)(kT + koff + (long)64 * 12288);

#pragma unroll 1
    for (int ks = 0; ks < 24; ++ks) {
        *(bf16x8*)&Qs[srow * 40 + sseg] = qr0;
        *(bf16x8*)&Qs[(64 + srow) * 40 + sseg] = qr1;
        *(bf16x8*)&Ks[srow * 40 + sseg] = kr0;
        *(bf16x8*)&Ks[(64 + srow) * 40 + sseg] = kr1;
        if (ks < 23) {
            long o = (long)(ks + 1) * 32;
            qr0 = *(const bf16x8*)(qT + qoff + o);
            qr1 = *(const bf16x8*)(qT + qoff + (long)64 * 12288 + o);
            kr0 = *(const bf16x8*)(kT + koff + o);
            kr1 = *(const bf16x8*)(kT + koff + (long)64 * 12288 + o);
        }
        __syncthreads();
        bf16x8 af[4], bfr[4];
#pragma unroll
        for (int fa = 0; fa < 4; ++fa)
            af[fa] = *(const bf16x8*)&Qs[(wm * 64 + fa * 16 + li) * 40 + lg * 8];
#pragma unroll
        for (int fb = 0; fb < 4; ++fb)
            bfr[fb] = *(const bf16x8*)&Ks[(wn * 64 + fb * 16 + li) * 40 + lg * 8];
#pragma unroll
        for (int fa = 0; fa < 4; ++fa)
#pragma unroll
            for (int fb = 0; fb < 4; ++fb)
                acc[fa][fb] = __builtin_amdgcn_mfma_f32_16x16x32_bf16(af[fa], bfr[fb], acc[fa][fb], 0, 0, 0);
        __syncthreads();
    }

    float* op = Sp + ((long)(sk * 8 + bh) << 16);
#pragma unroll
    for (int fa = 0; fa < 4; ++fa) {
        int i = i0 + wm * 64 + fa * 16 + lg * 4;
#pragma unroll
        for (int fb = 0; fb < 4; ++fb) {
            int j = j0 + wn * 64 + fb * 16 + li;
#pragma unroll
            for (int ii = 0; ii < 4; ++ii)
                op[(long)(i + ii) * 256 + j] = acc[fa][fb][ii];
        }
    }
}

// ---------------- softmax over i with scaling; writes Pt in vattn B-fragment layout.
__global__ __launch_bounds__(256) void softmax_k(const float* __restrict__ Sp, const float* __restrict__ norms,
                                                 const float* __restrict__ temp, unsigned short* __restrict__ Pt)
{
    __shared__ float Sd[256 * 9];
    __shared__ float red[32 * 9];
    int tid = threadIdx.x;
    int g = blockIdx.x; int bh = g >> 5, jq = g & 31; int b = bh >> 2, h = bh & 3;
    int jl = tid & 7, iq = tid >> 3;
    int j = jq * 8 + jl;
    const float* nq = norms + (b * 8 + h) * 256;
    float invkj = norms[(b * 8 + 4 + h) * 256 + j] * temp[h];
    const float* sp = Sp + (long)bh * HW + j;

    float m = -1e30f;
#pragma unroll
    for (int ii = 0; ii < 8; ++ii) {
        int i = iq * 8 + ii;
        float s = 0.f;
#pragma unroll
        for (int sk = 0; sk < 16; ++sk) s += sp[((long)(sk * 8) << 16) + i * 256];
        float v = s * nq[i] * invkj;
        Sd[i * 9 + jl] = v;
        m = fmaxf(m, v);
    }
    red[iq * 9 + jl] = m;
    __syncthreads();
    m = -1e30f;
#pragma unroll
    for (int s2 = 0; s2 < 32; ++s2) m = fmaxf(m, red[s2 * 9 + jl]);
    __syncthreads();
    float sum = 0.f;
#pragma unroll
    for (int ii = 0; ii < 8; ++ii) sum += __expf(Sd[(iq * 8 + ii) * 9 + jl] - m);
    red[iq * 9 + jl] = sum;
    __syncthreads();
    sum = 0.f;
#pragma unroll
    for (int s2 = 0; s2 < 32; ++s2) sum += red[s2 * 9 + jl];
    float rs = 1.0f / sum;

    int fb = jq >> 1, li2 = (jq & 1) * 8 + jl;
    int ks = iq >> 2, lg = iq & 3;
    unsigned short* pt = Pt + (long)bh * HW + (long)((fb * 8 + ks) * 64 + lg * 16 + li2) * 8;
    bf16x8 pv;
#pragma unroll
    for (int ii = 0; ii < 8; ++ii)
        pv[ii] = (short)f2b(__expf(Sd[(iq * 8 + ii) * 9 + jl] - m) * rs);
    *(bf16x8*)pt = pv;
}

// ---------------- vattn: P in fragment layout (coalesced 1KB loads), no LDS. grid (192, 8)
__global__ __launch_bounds__(256) void vattn(const unsigned short* __restrict__ vpl,
                                             const unsigned short* __restrict__ Pt,
                                             unsigned short* __restrict__ vout)
{
    int tid = threadIdx.x;
    int w = tid >> 6, lane = tid & 63, lg = lane >> 4, li = lane & 15;
    int wm = w >> 1, wn = w & 1;
    int m0 = blockIdx.x * 64 + wm * 32;
    int bh = blockIdx.y; int b = bh >> 2, h = bh & 3;
    const unsigned short* V = vpl + (long)(b * 192 + h * 48) * HW;
    const unsigned short* P = Pt + (long)bh * HW + wn * 32768 + lane * 8;

    f32x4 acc[2][8];
#pragma unroll
    for (int i = 0; i < 2; ++i)
#pragma unroll
        for (int j = 0; j < 8; ++j) acc[i][j] = (f32x4){0.f, 0.f, 0.f, 0.f};

#pragma unroll 2
    for (int ks = 0; ks < 8; ++ks) {
        bf16x8 a0 = *(const bf16x8*)(V + (long)(m0 + li) * 256 + ks * 32 + lg * 8);
        bf16x8 a1 = *(const bf16x8*)(V + (long)(m0 + 16 + li) * 256 + ks * 32 + lg * 8);
#pragma unroll
        for (int fb2 = 0; fb2 < 8; ++fb2) {
            bf16x8 bb = *(const bf16x8*)(P + (fb2 * 8 + ks) * 512);
            acc[0][fb2] = __builtin_amdgcn_mfma_f32_16x16x32_bf16(a0, bb, acc[0][fb2], 0, 0, 0);
            acc[1][fb2] = __builtin_amdgcn_mfma_f32_16x16x32_bf16(a1, bb, acc[1][fb2], 0, 0, 0);
        }
    }
    unsigned short* ob = vout + (long)(b * 192 + h * 48) * HW;
#pragma unroll
    for (int fa = 0; fa < 2; ++fa) {
#pragma unroll
        for (int fb2 = 0; fb2 < 8; ++fb2) {
            int j = (wn * 8 + fb2) * 16 + li;
#pragma unroll
            for (int ii = 0; ii < 4; ++ii) {
                int m = m0 + fa * 16 + lg * 4 + ii;
                ob[((long)(m >> 8) << 16) + ((m & 255) << 8) + j] = f2b(acc[fa][fb2][ii]);
            }
        }
    }
}

extern "C" void kernel_launch(void* const* d_in, const int* in_sizes, int n_in,
                              void* d_out, int out_size, void* d_ws, size_t ws_size,
                              hipStream_t stream)
{
    (void)in_sizes; (void)n_in; (void)out_size; (void)ws_size;
    const float* x      = (const float*)d_in[0];
    const float* w_qkv  = (const float*)d_in[1];
    const float* w_dw   = (const float*)d_in[2];
    const float* w_proj = (const float*)d_in[3];
    const float* temp   = (const float*)d_in[4];
    float* out = (float*)d_out;
    char* ws = (char*)d_ws;

    unsigned short* qkv_pre = (unsigned short*)(ws + OFF_A0);
    float*          Sp      = (float*)(ws + OFF_SP);
    unsigned short* vout    = (unsigned short*)(ws + OFF_A0);
    unsigned short* qkT     = (unsigned short*)(ws + OFF_QKT);
    unsigned short* vpl     = (unsigned short*)(ws + OFF_VPL);
    unsigned short* Pt      = (unsigned short*)(ws + OFF_PT);
    float*          norms   = (float*)(ws + OFF_NORMS);
    unsigned short* wqb     = (unsigned short*)(ws + OFF_WQ);
    unsigned short* wpb     = (unsigned short*)(ws + OFF_WP);

    conv_w<<<64, 256, 0, stream>>>(w_qkv, w_proj, wqb, wpb);
    gemm_pm3<0><<<1024, 256, 0, stream>>>(wqb, (const void*)x, qkv_pre, nullptr, 9);
    dwconv2<<<dim3(8, 1152), 256, 0, stream>>>(qkv_pre, w_dw, qkT, vpl);
    norms_k<<<dim3(256, 16), 256, 0, stream>>>(qkT, norms);
    attn_qk<<<dim3(2, 2, 128), 256, 0, stream>>>(qkT, Sp);
    softmax_k<<<256, 256, 0, stream>>>(Sp, norms, temp, Pt);
    vattn<<<dim3(192, 8), 256, 0, stream>>>(vpl, Pt, vout);
    gemm_pm3<1><<<1024, 256, 0, stream>>>(wpb, (const void*)vout, nullptr, out, 3);
}